// Round 4
// baseline (2294.647 us; speedup 1.0000x reference)
//
#include <hip/hip_runtime.h>

// ---------------- constants ----------------
#define HDIM 1024
#define BB 8
#define SS 1024
#define NHEAD 16
#define PFF 4096
#define NLAYER 6
#define MM (BB*SS)   // 8192 rows

typedef __attribute__((ext_vector_type(8))) short bf16x8_t;
typedef __attribute__((ext_vector_type(4))) float f32x4_t;
typedef __attribute__((ext_vector_type(16))) float f32x16_t;

static __device__ __forceinline__ unsigned short f2b(float f) {
  unsigned int u = __float_as_uint(f);
  u += 0x7fffu + ((u >> 16) & 1u);      // RNE
  return (unsigned short)(u >> 16);
}

static __device__ __forceinline__ unsigned pkbf(float lo, float hi) {
  unsigned r;
  asm("v_cvt_pk_bf16_f32 %0, %1, %2" : "=v"(r) : "v"(lo), "v"(hi));
  return r;
}

static __device__ __forceinline__ bf16x8_t mk8(unsigned a, unsigned b, unsigned c, unsigned d) {
  union { unsigned u[4]; bf16x8_t v; } x;
  x.u[0] = a; x.u[1] = b; x.u[2] = c; x.u[3] = d;
  return x.v;
}

static __device__ __forceinline__ void gload16(const void* g, void* l) {
  __builtin_amdgcn_global_load_lds((__attribute__((address_space(1))) void*)g,
                                   (__attribute__((address_space(3))) void*)l, 16, 0, 0);
}

template<int N>
static __device__ __forceinline__ void vwait() {
  asm volatile("s_waitcnt vmcnt(%0)" :: "n"(N) : "memory");
}

static __device__ __forceinline__ void bar() {
  asm volatile("" ::: "memory");
  __builtin_amdgcn_s_barrier();
  asm volatile("" ::: "memory");
}

// ---------------- fp32 -> bf16 convert ----------------
__global__ __launch_bounds__(256) void cvt_bf16(const float* __restrict__ in,
                                                unsigned short* __restrict__ o, int n4) {
  const int i = blockIdx.x * 256 + threadIdx.x;
  if (i < n4) {
    const float4 v = ((const float4*)in)[i];
    ushort4 ob = { f2b(v.x), f2b(v.y), f2b(v.z), f2b(v.w) };
    ((ushort4*)o)[i] = ob;
  }
}

// ---------------- transpose fp32 [R][C] -> bf16 [C][R] ----------------
__global__ __launch_bounds__(256) void transpose_bf16(const float* __restrict__ in,
                                                      unsigned short* __restrict__ outT,
                                                      int R, int C) {
  __shared__ float tile[32][33];
  const int c0 = blockIdx.x * 32, r0 = blockIdx.y * 32;
  const int tx = threadIdx.x, ty = threadIdx.y;   // (32,8)
#pragma unroll
  for (int i = 0; i < 4; ++i)
    tile[ty + 8*i][tx] = in[(size_t)(r0 + ty + 8*i) * C + c0 + tx];
  __syncthreads();
#pragma unroll
  for (int i = 0; i < 4; ++i)
    outT[(size_t)(c0 + ty + 8*i) * R + r0 + tx] = f2b(tile[tx][ty + 8*i]);
}

// ---------------- V^T extraction: qkv[M][3072] (V at col 2048+) -> vt[bh][64][1024] ----------------
__global__ __launch_bounds__(256) void vtrans(const unsigned short* __restrict__ qkv,
                                              unsigned short* __restrict__ vt) {
  __shared__ unsigned short tile[32][34];
  const int s0 = blockIdx.x * 32;
  const int by = blockIdx.y;           // bh*2 + dt
  const int bh = by >> 1, dt = by & 1;
  const int b = bh >> 4, h = bh & 15;
  const int tx = threadIdx.x, ty = threadIdx.y;  // (32,8)
  const unsigned short* src = qkv + ((size_t)(b * 1024 + s0)) * 3072 + 2048 + h * 64 + dt * 32;
#pragma unroll
  for (int i = 0; i < 4; ++i)
    tile[ty + 8*i][tx] = src[(size_t)(ty + 8*i) * 3072 + tx];
  __syncthreads();
  unsigned short* dst = vt + (size_t)(bh * 64 + dt * 32) * 1024 + s0;
#pragma unroll
  for (int i = 0; i < 4; ++i)
    dst[(size_t)(ty + 8*i) * 1024 + tx] = tile[tx][ty + 8*i];
}

// ---------------- bias concat for fused QKV ----------------
__global__ __launch_bounds__(256) void concat_bias(const float* __restrict__ bq,
                                                   const float* __restrict__ bk,
                                                   const float* __restrict__ bv,
                                                   float* __restrict__ o) {
  const int i = blockIdx.x * 256 + threadIdx.x;   // 0..3071
  o[i] = (i < 1024) ? bq[i] : ((i < 2048) ? bk[i - 1024] : bv[i - 2048]);
}

// ---------------- GEMM 256xBN, 8 waves (4x2), 32x32x16 MFMA ----------------
// Interleaved schedule w/ counted vmcnt (never drains in steady state):
//   BN=256: groups g0=[Bc0,Bc1] g1=[Ai0,Ai1] g2=[Ai2,Ai3,Bc2,Bc3]
//           S0: vmcnt(4) bar issue(g0) read(A-rb0,B-cb01) mfma
//           S1: vmcnt(2) bar issue(g1) read(A-rb1) mfma issue(g2) read(B-cb23) mfma x2
//   BN=128: g0=[Ai0..3,Bc0] g1=[Bc1];  S0: vmcnt(1), S1: vmcnt(5)
// LDS: dbuf x (A 32KB | B BN*128B), XOR-swizzle (row&7)<<4 both sides.
template<int BN, bool BIAS, bool RELU, bool RESID, bool EMB, bool WF32, bool WBF16>
__global__ __launch_bounds__(512, 2) void gemm8p(
    const unsigned short* __restrict__ A,
    const unsigned short* __restrict__ Bt,
    const float* __restrict__ bias,
    const float* __restrict__ resid,
    const float* __restrict__ pos,
    float* __restrict__ outf,
    unsigned short* __restrict__ outb,
    int M, int N, int K) {
  constexpr int NCB = BN / 64;                   // col-blocks per wave (4 or 2)
  constexpr int BUFSZ = 32768 + BN * 128;
  __shared__ __align__(1024) char smem[2 * BUFSZ];
  const int t = threadIdx.x, lane = t & 63, w = t >> 6;
  const int l31 = lane & 31, lg = lane >> 5;
  const int wr = w >> 1, wc = w & 1;             // 4x2 wave grid

  // bijective XCD swizzle (all grids divisible by 8)
  int flat = blockIdx.x + gridDim.x * blockIdx.y;
  const int cpx = (gridDim.x * gridDim.y) >> 3;
  flat = (flat & 7) * cpx + (flat >> 3);
  const int m0 = (flat / gridDim.x) * 256;
  const int n0 = (flat % gridDim.x) * BN;

  const size_t Kb = (size_t)K * 2;               // row stride bytes
  const int ric = lane >> 3;                     // staged row-in-chunk
  const int scb = ((lane & 7) * 16) ^ ((ric & 7) << 4);  // inverse swizzle on source

  // staging bases: A chunk i -> rows m0+wr*64+wc*8+i*16 ; B chunk c -> cols n0+wc*(BN/2)+wr*8+c*32
  const char* gA0 = (const char*)A  + (size_t)(m0 + wr * 64 + wc * 8 + ric) * Kb + scb;
  const char* gB0 = (const char*)Bt + (size_t)(n0 + wc * (BN / 2) + wr * 8 + ric) * Kb + scb;
  const int lA0 = (wr * 64 + wc * 8) * 128;
  const int lB0 = 32768 + (wc * (BN / 2) + wr * 8) * 128;

  const f32x16_t z16 = {0.f};
  f32x16_t acc[2][NCB];
#pragma unroll
  for (int i = 0; i < 2; ++i)
#pragma unroll
    for (int j = 0; j < NCB; ++j) acc[i][j] = z16;

  const int arow = wr * 64 + l31;                // + rb*32
  const int bcol = wc * (BN / 2) + l31;          // + cb*32
  const int sw = (l31 & 7) << 4;
  const int kx = lg * 16;                        // + ks*32, XOR sw

  const int nkt = K >> 6;

#define STA(i, kt, buf) gload16(gA0 + (size_t)(i) * 16 * Kb + ((size_t)(kt) << 7), \
                                smem + (buf) * BUFSZ + lA0 + (i) * 2048)
#define STB(c, kt, buf) gload16(gB0 + (size_t)(c) * 32 * Kb + ((size_t)(kt) << 7), \
                                smem + (buf) * BUFSZ + lB0 + (c) * 4096)

  // prologue: tile 0, group order
  if constexpr (BN == 256) {
    STB(0, 0, 0); STB(1, 0, 0);
    STA(0, 0, 0); STA(1, 0, 0);
    STA(2, 0, 0); STA(3, 0, 0); STB(2, 0, 0); STB(3, 0, 0);
  } else {
    STA(0, 0, 0); STA(1, 0, 0); STA(2, 0, 0); STA(3, 0, 0); STB(0, 0, 0);
    STB(1, 0, 0);
  }

  bf16x8_t af[2][4];   // [rb][ks], live whole tile
  bf16x8_t bfr[2][4];  // [cb-in-group][ks]

  for (int kt = 0; kt < nkt; ++kt) {
    const char* ab = smem + (kt & 1) * BUFSZ;
    const char* bb = ab + 32768;
    const int nb = (kt & 1) ^ 1;
    const bool pf = (kt + 1 < nkt);

    if constexpr (BN == 256) {
      // ---- S0: needs Bc01(g0), A-rb0(g1); g2 may be in flight ----
      vwait<4>(); bar();
      if (pf) { STB(0, kt + 1, nb); STB(1, kt + 1, nb); }
#pragma unroll
      for (int ks = 0; ks < 4; ++ks)
        af[0][ks] = *(const bf16x8_t*)(ab + arow * 128 + ((ks * 32 + kx) ^ sw));
#pragma unroll
      for (int c = 0; c < 2; ++c)
#pragma unroll
        for (int ks = 0; ks < 4; ++ks)
          bfr[c][ks] = *(const bf16x8_t*)(bb + (bcol + c * 32) * 128 + ((ks * 32 + kx) ^ sw));
      __builtin_amdgcn_s_setprio(1);
#pragma unroll
      for (int ks = 0; ks < 4; ++ks)
#pragma unroll
        for (int c = 0; c < 2; ++c)
          acc[0][c] = __builtin_amdgcn_mfma_f32_32x32x16_bf16(af[0][ks], bfr[c][ks], acc[0][c], 0, 0, 0);
      __builtin_amdgcn_s_setprio(0);
      // ---- S1: needs A-rb1, B-cb23 (g2) ----
      vwait<2>(); bar();
      if (pf) { STA(0, kt + 1, nb); STA(1, kt + 1, nb); }
#pragma unroll
      for (int ks = 0; ks < 4; ++ks)
        af[1][ks] = *(const bf16x8_t*)(ab + (arow + 32) * 128 + ((ks * 32 + kx) ^ sw));
      __builtin_amdgcn_s_setprio(1);
#pragma unroll
      for (int ks = 0; ks < 4; ++ks)
#pragma unroll
        for (int c = 0; c < 2; ++c)
          acc[1][c] = __builtin_amdgcn_mfma_f32_32x32x16_bf16(af[1][ks], bfr[c][ks], acc[1][c], 0, 0, 0);
      __builtin_amdgcn_s_setprio(0);
      if (pf) { STA(2, kt + 1, nb); STA(3, kt + 1, nb); STB(2, kt + 1, nb); STB(3, kt + 1, nb); }
#pragma unroll
      for (int c = 0; c < 2; ++c)
#pragma unroll
        for (int ks = 0; ks < 4; ++ks)
          bfr[c][ks] = *(const bf16x8_t*)(bb + (bcol + (c + 2) * 32) * 128 + ((ks * 32 + kx) ^ sw));
      __builtin_amdgcn_s_setprio(1);
#pragma unroll
      for (int ks = 0; ks < 4; ++ks)
#pragma unroll
        for (int c = 0; c < 2; ++c) {
          acc[0][c + 2] = __builtin_amdgcn_mfma_f32_32x32x16_bf16(af[0][ks], bfr[c][ks], acc[0][c + 2], 0, 0, 0);
          acc[1][c + 2] = __builtin_amdgcn_mfma_f32_32x32x16_bf16(af[1][ks], bfr[c][ks], acc[1][c + 2], 0, 0, 0);
        }
      __builtin_amdgcn_s_setprio(0);
    } else {
      // ---- BN=128. S0: needs A(all)+Bc0 (g0) ----
      vwait<1>(); bar();
      if (pf) { STA(0, kt + 1, nb); STA(1, kt + 1, nb); STA(2, kt + 1, nb); STA(3, kt + 1, nb); STB(0, kt + 1, nb); }
#pragma unroll
      for (int rb = 0; rb < 2; ++rb)
#pragma unroll
        for (int ks = 0; ks < 4; ++ks)
          af[rb][ks] = *(const bf16x8_t*)(ab + (arow + rb * 32) * 128 + ((ks * 32 + kx) ^ sw));
#pragma unroll
      for (int ks = 0; ks < 4; ++ks)
        bfr[0][ks] = *(const bf16x8_t*)(bb + bcol * 128 + ((ks * 32 + kx) ^ sw));
      __builtin_amdgcn_s_setprio(1);
#pragma unroll
      for (int ks = 0; ks < 4; ++ks)
#pragma unroll
        for (int rb = 0; rb < 2; ++rb)
          acc[rb][0] = __builtin_amdgcn_mfma_f32_32x32x16_bf16(af[rb][ks], bfr[0][ks], acc[rb][0], 0, 0, 0);
      __builtin_amdgcn_s_setprio(0);
      // ---- S1: needs Bc1 (g1) ----
      vwait<5>(); bar();
      if (pf) { STB(1, kt + 1, nb); }
#pragma unroll
      for (int ks = 0; ks < 4; ++ks)
        bfr[1][ks] = *(const bf16x8_t*)(bb + (bcol + 32) * 128 + ((ks * 32 + kx) ^ sw));
      __builtin_amdgcn_s_setprio(1);
#pragma unroll
      for (int ks = 0; ks < 4; ++ks)
#pragma unroll
        for (int rb = 0; rb < 2; ++rb)
          acc[rb][1] = __builtin_amdgcn_mfma_f32_32x32x16_bf16(af[rb][ks], bfr[1][ks], acc[rb][1], 0, 0, 0);
      __builtin_amdgcn_s_setprio(0);
    }
  }
#undef STA
#undef STB

  // epilogue: 32x32 C/D layout: col=lane&31, row=(r&3)+8*(r>>2)+4*lg
#pragma unroll
  for (int rb = 0; rb < 2; ++rb) {
#pragma unroll
    for (int cb = 0; cb < NCB; ++cb) {
      const int cc = n0 + wc * (BN / 2) + cb * 32 + l31;
      float bv = 0.f;
      if (BIAS) bv = bias[cc];
#pragma unroll
      for (int r = 0; r < 16; ++r) {
        const int row = m0 + wr * 64 + rb * 32 + (r & 3) + 8 * (r >> 2) + 4 * lg;
        float v = acc[rb][cb][r] + bv;
        if (EMB)  v = v * 32.f + pos[(size_t)(row & (SS - 1)) * N + cc];
        if (RELU) v = fmaxf(v, 0.f);
        if (RESID) v += resid[(size_t)row * N + cc];
        if (WF32)  outf[(size_t)row * N + cc] = v;
        if (WBF16) outb[(size_t)row * N + cc] = f2b(v);
      }
    }
  }
}

// ---------------- flash attention, swapped-QK^T in-register softmax ----------------
__global__ __launch_bounds__(256) void attn2(
    const unsigned short* __restrict__ qkv,   // [M][3072]: Q|K|V
    const unsigned short* __restrict__ vt,    // [bh][64][1024] = V^T per head
    unsigned short* __restrict__ O) {         // [M][1024]
  __shared__ __align__(1024) char smem[2 * 16384];   // dbuf x (K 8KB | VT 8KB)
  const int t = threadIdx.x, lane = t & 63, w = t >> 6;
  const int l31 = lane & 31, lg = lane >> 5;   // lane group (0/1)
  const int bh = blockIdx.y;
  const int b = bh >> 4, h = bh & 15;
  const size_t rowb = (size_t)b << 10;
  const int q0 = blockIdx.x * 128 + w * 32;

  bf16x8_t qf[4];
  {
    const unsigned short* Qp = qkv + (rowb + q0 + l31) * 3072 + h * 64 + lg * 8;
#pragma unroll
    for (int dd = 0; dd < 4; ++dd) qf[dd] = *(const bf16x8_t*)(Qp + dd * 16);
  }

  f32x16_t oa0, oa1;
#pragma unroll
  for (int r = 0; r < 16; ++r) { oa0[r] = 0.f; oa1[r] = 0.f; }
  float m_run = -1e30f, l_run = 0.f;
  const float inv32 = 1.f / 32.f;

  const char* kglob = (const char*)qkv + ((size_t)1024 + h * 64) * 2;
  const char* vglob = (const char*)vt + (size_t)bh * 64 * 1024 * 2;

  auto stage = [&](int kt, int buf) {
    char* kbuf = smem + buf * 16384;
    char* vbuf = kbuf + 8192;
#pragma unroll
    for (int i = 0; i < 2; ++i) {
      const int chunk = w * 2 + i;                 // 0..7
      const int byteoff = chunk * 1024 + lane * 16;
      const int row = byteoff >> 7;                // 0..63
      const int scb = (byteoff & 127) ^ ((row & 7) << 4);
      gload16(kglob + (size_t)(rowb + kt * 64 + row) * 6144 + scb, kbuf + chunk * 1024);
      gload16(vglob + ((size_t)row * 1024 + kt * 64) * 2 + scb,    vbuf + chunk * 1024);
    }
  };

  stage(0, 0);
  for (int kt = 0; kt < 16; ++kt) {
    const int cb = kt & 1;
    __syncthreads();
    if (kt < 15) stage(kt + 1, cb ^ 1);
    const char* kbuf = smem + cb * 16384;
    const char* vbuf = kbuf + 8192;

    f32x16_t p0, p1;
#pragma unroll
    for (int r = 0; r < 16; ++r) { p0[r] = 0.f; p1[r] = 0.f; }
    __builtin_amdgcn_s_setprio(1);
#pragma unroll
    for (int dd = 0; dd < 4; ++dd) {
      {
        const int row = l31;
        const int col = (dd * 32 + (lg << 4)) ^ ((row & 7) << 4);
        bf16x8_t kf = *(const bf16x8_t*)(kbuf + row * 128 + col);
        p0 = __builtin_amdgcn_mfma_f32_32x32x16_bf16(kf, qf[dd], p0, 0, 0, 0);
      }
      {
        const int row = 32 + l31;
        const int col = (dd * 32 + (lg << 4)) ^ ((row & 7) << 4);
        bf16x8_t kf = *(const bf16x8_t*)(kbuf + row * 128 + col);
        p1 = __builtin_amdgcn_mfma_f32_32x32x16_bf16(kf, qf[dd], p1, 0, 0, 0);
      }
    }
    __builtin_amdgcn_s_setprio(0);

    float mx = p0[0];
#pragma unroll
    for (int r = 1; r < 16; ++r) mx = fmaxf(mx, p0[r]);
#pragma unroll
    for (int r = 0; r < 16; ++r) mx = fmaxf(mx, p1[r]);
    mx = fmaxf(mx, __shfl_xor(mx, 32));
    const float mn = fmaxf(m_run, mx * inv32);
    const float fr = __expf(m_run - mn);
    m_run = mn;
    float sum = 0.f;
#pragma unroll
    for (int r = 0; r < 16; ++r) { const float e = __expf(p0[r] * inv32 - mn); p0[r] = e; sum += e; }
#pragma unroll
    for (int r = 0; r < 16; ++r) { const float e = __expf(p1[r] * inv32 - mn); p1[r] = e; sum += e; }
    sum += __shfl_xor(sum, 32);
    l_run = l_run * fr + sum;
#pragma unroll
    for (int r = 0; r < 16; ++r) { oa0[r] *= fr; oa1[r] *= fr; }

    const unsigned A0 = pkbf(p0[0], p0[1]),  B0 = pkbf(p0[2], p0[3]);
    const unsigned C0 = pkbf(p0[4], p0[5]),  D0 = pkbf(p0[6], p0[7]);
    const unsigned E0 = pkbf(p0[8], p0[9]),  F0 = pkbf(p0[10], p0[11]);
    const unsigned G0 = pkbf(p0[12], p0[13]), H0 = pkbf(p0[14], p0[15]);
    const unsigned A1 = pkbf(p1[0], p1[1]),  B1 = pkbf(p1[2], p1[3]);
    const unsigned C1 = pkbf(p1[4], p1[5]),  D1 = pkbf(p1[6], p1[7]);
    const unsigned E1 = pkbf(p1[8], p1[9]),  F1 = pkbf(p1[10], p1[11]);
    const unsigned G1 = pkbf(p1[12], p1[13]), H1 = pkbf(p1[14], p1[15]);
    const unsigned sA0 = __shfl_xor((int)A0, 32), sB0 = __shfl_xor((int)B0, 32);
    const unsigned sC0 = __shfl_xor((int)C0, 32), sD0 = __shfl_xor((int)D0, 32);
    const unsigned sE0 = __shfl_xor((int)E0, 32), sF0 = __shfl_xor((int)F0, 32);
    const unsigned sG0 = __shfl_xor((int)G0, 32), sH0 = __shfl_xor((int)H0, 32);
    const unsigned sA1 = __shfl_xor((int)A1, 32), sB1 = __shfl_xor((int)B1, 32);
    const unsigned sC1 = __shfl_xor((int)C1, 32), sD1 = __shfl_xor((int)D1, 32);
    const unsigned sE1 = __shfl_xor((int)E1, 32), sF1 = __shfl_xor((int)F1, 32);
    const unsigned sG1 = __shfl_xor((int)G1, 32), sH1 = __shfl_xor((int)H1, 32);
    const bool hi = (lg != 0);
    bf16x8_t pf[4];
    pf[0] = hi ? mk8(sC0, sD0, C0, D0) : mk8(A0, B0, sA0, sB0);
    pf[1] = hi ? mk8(sG0, sH0, G0, H0) : mk8(E0, F0, sE0, sF0);
    pf[2] = hi ? mk8(sC1, sD1, C1, D1) : mk8(A1, B1, sA1, sB1);
    pf[3] = hi ? mk8(sG1, sH1, G1, H1) : mk8(E1, F1, sE1, sF1);

    __builtin_amdgcn_s_setprio(1);
#pragma unroll
    for (int c = 0; c < 4; ++c) {
      {
        const int row = l31;
        const int col = (c * 32 + (lg << 4)) ^ ((row & 7) << 4);
        bf16x8_t vf = *(const bf16x8_t*)(vbuf + row * 128 + col);
        oa0 = __builtin_amdgcn_mfma_f32_32x32x16_bf16(vf, pf[c], oa0, 0, 0, 0);
      }
      {
        const int row = 32 + l31;
        const int col = (c * 32 + (lg << 4)) ^ ((row & 7) << 4);
        bf16x8_t vf = *(const bf16x8_t*)(vbuf + row * 128 + col);
        oa1 = __builtin_amdgcn_mfma_f32_32x32x16_bf16(vf, pf[c], oa1, 0, 0, 0);
      }
    }
    __builtin_amdgcn_s_setprio(0);
  }

  const float inv = 1.f / l_run;
  unsigned short* op = O + (rowb + q0 + l31) * 1024 + h * 64 + (lg << 2);
#pragma unroll
  for (int rg = 0; rg < 4; ++rg) {
    const unsigned u0 = pkbf(oa0[rg * 4 + 0] * inv, oa0[rg * 4 + 1] * inv);
    const unsigned u1 = pkbf(oa0[rg * 4 + 2] * inv, oa0[rg * 4 + 3] * inv);
    uint2 st = { u0, u1 };
    *(uint2*)(op + rg * 8) = st;
    const unsigned v0 = pkbf(oa1[rg * 4 + 0] * inv, oa1[rg * 4 + 1] * inv);
    const unsigned v1 = pkbf(oa1[rg * 4 + 2] * inv, oa1[rg * 4 + 3] * inv);
    uint2 st2 = { v0, v1 };
    *(uint2*)(op + 32 + rg * 8) = st2;
  }
}

// ---------------- LayerNorm: fp32 in -> fp32 + bf16 out ----------------
__global__ __launch_bounds__(256) void ln_kernel(
    const float* __restrict__ y, const float* __restrict__ g, const float* __restrict__ be,
    float* __restrict__ xf, unsigned short* __restrict__ xb) {
  const int row = blockIdx.x;
  const int t = threadIdx.x;
  const float4 v = ((const float4*)(y + (size_t)row * HDIM))[t];
  float s  = v.x + v.y + v.z + v.w;
  float ss = v.x*v.x + v.y*v.y + v.z*v.z + v.w*v.w;
#pragma unroll
  for (int m = 1; m < 64; m <<= 1) { s += __shfl_xor(s, m); ss += __shfl_xor(ss, m); }
  __shared__ float rs[4], rss[4];
  const int w = t >> 6, lane = t & 63;
  if (lane == 0) { rs[w] = s; rss[w] = ss; }
  __syncthreads();
  s  = rs[0] + rs[1] + rs[2] + rs[3];
  ss = rss[0] + rss[1] + rss[2] + rss[3];
  const float mean = s * (1.f / HDIM);
  const float inv = rsqrtf(ss * (1.f / HDIM) - mean * mean + 1e-5f);
  const int c = t * 4;
  const float4 gg = *(const float4*)(g + c);
  const float4 bb = *(const float4*)(be + c);
  float4 o;
  o.x = (v.x - mean) * inv * gg.x + bb.x;
  o.y = (v.y - mean) * inv * gg.y + bb.y;
  o.z = (v.z - mean) * inv * gg.z + bb.z;
  o.w = (v.w - mean) * inv * gg.w + bb.w;
  ((float4*)(xf + (size_t)row * HDIM))[t] = o;
  ushort4 ob = { f2b(o.x), f2b(o.y), f2b(o.z), f2b(o.w) };
  ((ushort4*)(xb + (size_t)row * HDIM))[t] = ob;
}

// ---------------- host ----------------
extern "C" void kernel_launch(void* const* d_in, const int* in_sizes, int n_in,
                              void* d_out, int out_size, void* d_ws, size_t ws_size,
                              hipStream_t stream) {
  const float* input_x = (const float*)d_in[0];
  const float* emb_W   = (const float*)d_in[1];
  const float* emb_b   = (const float*)d_in[2];
  const float* pos_tab = (const float*)d_in[3];
  const float* Wq  = (const float*)d_in[4];
  const float* bq  = (const float*)d_in[5];
  const float* Wk  = (const float*)d_in[6];
  const float* bk  = (const float*)d_in[7];
  const float* Wv  = (const float*)d_in[8];
  const float* bv  = (const float*)d_in[9];
  const float* Wo  = (const float*)d_in[10];
  const float* bo  = (const float*)d_in[11];
  const float* ln1g = (const float*)d_in[12];
  const float* ln1b = (const float*)d_in[13];
  const float* W1  = (const float*)d_in[14];
  const float* b1  = (const float*)d_in[15];
  const float* W2  = (const float*)d_in[16];
  const float* b2  = (const float*)d_in[17];
  const float* ln2g = (const float*)d_in[18];
  const float* ln2b = (const float*)d_in[19];
  float* out = (float*)d_out;

  char* ws = (char*)d_ws;
  size_t off = 0;
  auto alloc = [&](size_t bytes) {
    char* p = ws + off;
    off += (bytes + 255) & ~(size_t)255;
    return p;
  };
  unsigned short* wqkvT = (unsigned short*)alloc((size_t)3072 * HDIM * 2);
  unsigned short* woT   = (unsigned short*)alloc((size_t)HDIM * HDIM * 2);
  unsigned short* w1T   = (unsigned short*)alloc((size_t)PFF * HDIM * 2);   // [PF][H]
  unsigned short* w2T   = (unsigned short*)alloc((size_t)HDIM * PFF * 2);   // [H][PF]
  unsigned short* embWT = (unsigned short*)alloc((size_t)HDIM * 256 * 2);   // [H][IN]
  float*          bqkv  = (float*)alloc(3072 * 4);
  unsigned short* inb   = (unsigned short*)alloc((size_t)MM * 256 * 2);
  unsigned short* xb    = (unsigned short*)alloc((size_t)MM * HDIM * 2);
  unsigned short* qkvb  = (unsigned short*)alloc((size_t)MM * 3072 * 2);    // 48MB
  unsigned short* vtb   = (unsigned short*)alloc((size_t)MM * HDIM * 2);    // 16MB
  unsigned short* ab    = (unsigned short*)alloc((size_t)MM * HDIM * 2);
  float* y = (float*)alloc((size_t)MM * HDIM * 4);
  unsigned short* hb = qkvb;   // FFN hidden [M][4096] spans qkvb+vtb (dead by FFN1)

  const dim3 blk256(256);
  const dim3 blk512(512);
  const dim3 tblk(32, 8);

  // prep
  cvt_bf16<<<dim3(MM * 256 / 4 / 256), blk256, 0, stream>>>(input_x, inb, MM * 256 / 4);
  transpose_bf16<<<dim3(HDIM / 32, 256 / 32), tblk, 0, stream>>>(emb_W, embWT, 256, HDIM);

  // embedding: x = (input @ embW + b)*32 + pos   -> out(fp32) + xb(bf16)
  gemm8p<128, true, false, false, true, true, true><<<dim3(HDIM / 128, MM / 256), blk512, 0, stream>>>(
      inb, embWT, emb_b, nullptr, pos_tab, out, xb, MM, HDIM, 256);

  for (int l = 0; l < NLAYER; ++l) {
    const size_t wofs = (size_t)l * HDIM * HDIM;
    transpose_bf16<<<dim3(32, 32), tblk, 0, stream>>>(Wq + wofs, wqkvT,               HDIM, HDIM);
    transpose_bf16<<<dim3(32, 32), tblk, 0, stream>>>(Wk + wofs, wqkvT + 1024 * 1024, HDIM, HDIM);
    transpose_bf16<<<dim3(32, 32), tblk, 0, stream>>>(Wv + wofs, wqkvT + 2048 * 1024, HDIM, HDIM);
    transpose_bf16<<<dim3(32, 32), tblk, 0, stream>>>(Wo + wofs, woT, HDIM, HDIM);
    transpose_bf16<<<dim3(PFF / 32, HDIM / 32), tblk, 0, stream>>>(
        W1 + (size_t)l * HDIM * PFF, w1T, HDIM, PFF);
    transpose_bf16<<<dim3(HDIM / 32, PFF / 32), tblk, 0, stream>>>(
        W2 + (size_t)l * PFF * HDIM, w2T, PFF, HDIM);
    concat_bias<<<dim3(12), blk256, 0, stream>>>(bq + l * HDIM, bk + l * HDIM, bv + l * HDIM, bqkv);

    // fused QKV GEMM -> qkvb [M][3072]
    gemm8p<256, true, false, false, false, false, true><<<dim3(3072 / 256, MM / 256), blk512, 0, stream>>>(
        xb, wqkvT, bqkv, nullptr, nullptr, nullptr, qkvb, MM, 3072, HDIM);

    // V^T per head
    vtrans<<<dim3(32, 256), tblk, 0, stream>>>(qkvb, vtb);

    // attention
    attn2<<<dim3(SS / 128, BB * NHEAD), blk256, 0, stream>>>(qkvb, vtb, ab);

    // O-proj + residual (resid = fp32 x in `out`)
    gemm8p<128, true, false, true, false, true, false><<<dim3(HDIM / 128, MM / 256), blk512, 0, stream>>>(
        ab, woT, bo + l * HDIM, out, nullptr, y, nullptr, MM, HDIM, HDIM);
    ln_kernel<<<dim3(MM), blk256, 0, stream>>>(y, ln1g + l * HDIM, ln1b + l * HDIM, out, xb);

    // FFN
    gemm8p<256, true, true, false, false, false, true><<<dim3(PFF / 256, MM / 256), blk512, 0, stream>>>(
        xb, w1T, b1 + (size_t)l * PFF, nullptr, nullptr, nullptr, hb, MM, PFF, HDIM);
    gemm8p<128, true, false, true, false, true, false><<<dim3(HDIM / 128, MM / 256), blk512, 0, stream>>>(
        hb, w2T, b2 + l * HDIM, out, nullptr, y, nullptr, MM, HDIM, PFF);
    ln_kernel<<<dim3(MM), blk256, 0, stream>>>(y, ln2g + l * HDIM, ln2b + l * HDIM, out, xb);
  }
  (void)in_sizes; (void)n_in; (void)out_size; (void)ws_size;
}

// Round 5
// 2238.994 us; speedup vs baseline: 1.0249x; 1.0249x over previous
//
#include <hip/hip_runtime.h>

// ---------------- constants ----------------
#define HDIM 1024
#define BB 8
#define SS 1024
#define NHEAD 16
#define PFF 4096
#define NLAYER 6
#define MM (BB*SS)   // 8192 rows

typedef __attribute__((ext_vector_type(8))) short bf16x8_t;
typedef __attribute__((ext_vector_type(4))) float f32x4_t;
typedef __attribute__((ext_vector_type(16))) float f32x16_t;

static __device__ __forceinline__ unsigned short f2b(float f) {
  unsigned int u = __float_as_uint(f);
  u += 0x7fffu + ((u >> 16) & 1u);      // RNE
  return (unsigned short)(u >> 16);
}

static __device__ __forceinline__ unsigned pkbf(float lo, float hi) {
  unsigned r;
  asm("v_cvt_pk_bf16_f32 %0, %1, %2" : "=v"(r) : "v"(lo), "v"(hi));
  return r;
}

static __device__ __forceinline__ bf16x8_t mk8(unsigned a, unsigned b, unsigned c, unsigned d) {
  union { unsigned u[4]; bf16x8_t v; } x;
  x.u[0] = a; x.u[1] = b; x.u[2] = c; x.u[3] = d;
  return x.v;
}

static __device__ __forceinline__ void gload16(const void* g, void* l) {
  __builtin_amdgcn_global_load_lds((__attribute__((address_space(1))) void*)g,
                                   (__attribute__((address_space(3))) void*)l, 16, 0, 0);
}

template<int N>
static __device__ __forceinline__ void vwait() {
  asm volatile("s_waitcnt vmcnt(%0)" :: "n"(N) : "memory");
}

static __device__ __forceinline__ void bar() {
  asm volatile("" ::: "memory");
  __builtin_amdgcn_s_barrier();
  asm volatile("" ::: "memory");
}

// ---------------- fp32 -> bf16 convert ----------------
__global__ __launch_bounds__(256) void cvt_bf16(const float* __restrict__ in,
                                                unsigned short* __restrict__ o, int n4) {
  const int i = blockIdx.x * 256 + threadIdx.x;
  if (i < n4) {
    const float4 v = ((const float4*)in)[i];
    ushort4 ob = { f2b(v.x), f2b(v.y), f2b(v.z), f2b(v.w) };
    ((ushort4*)o)[i] = ob;
  }
}

// ---------------- transpose fp32 [R][C] -> bf16 [C][R] ----------------
__global__ __launch_bounds__(256) void transpose_bf16(const float* __restrict__ in,
                                                      unsigned short* __restrict__ outT,
                                                      int R, int C) {
  __shared__ float tile[32][33];
  const int c0 = blockIdx.x * 32, r0 = blockIdx.y * 32;
  const int tx = threadIdx.x, ty = threadIdx.y;   // (32,8)
#pragma unroll
  for (int i = 0; i < 4; ++i)
    tile[ty + 8*i][tx] = in[(size_t)(r0 + ty + 8*i) * C + c0 + tx];
  __syncthreads();
#pragma unroll
  for (int i = 0; i < 4; ++i)
    outT[(size_t)(c0 + ty + 8*i) * R + r0 + tx] = f2b(tile[tx][ty + 8*i]);
}

// ---------------- V^T extraction: qkv[M][3072] (V at col 2048+) -> vt[bh][64][1024] ----------------
__global__ __launch_bounds__(256) void vtrans(const unsigned short* __restrict__ qkv,
                                              unsigned short* __restrict__ vt) {
  __shared__ unsigned short tile[32][34];
  const int s0 = blockIdx.x * 32;
  const int by = blockIdx.y;           // bh*2 + dt
  const int bh = by >> 1, dt = by & 1;
  const int b = bh >> 4, h = bh & 15;
  const int tx = threadIdx.x, ty = threadIdx.y;  // (32,8)
  const unsigned short* src = qkv + ((size_t)(b * 1024 + s0)) * 3072 + 2048 + h * 64 + dt * 32;
#pragma unroll
  for (int i = 0; i < 4; ++i)
    tile[ty + 8*i][tx] = src[(size_t)(ty + 8*i) * 3072 + tx];
  __syncthreads();
  unsigned short* dst = vt + (size_t)(bh * 64 + dt * 32) * 1024 + s0;
#pragma unroll
  for (int i = 0; i < 4; ++i)
    dst[(size_t)(ty + 8*i) * 1024 + tx] = tile[tx][ty + 8*i];
}

// ---------------- bias concat for fused QKV ----------------
__global__ __launch_bounds__(256) void concat_bias(const float* __restrict__ bq,
                                                   const float* __restrict__ bk,
                                                   const float* __restrict__ bv,
                                                   float* __restrict__ o) {
  const int i = blockIdx.x * 256 + threadIdx.x;   // 0..3071
  o[i] = (i < 1024) ? bq[i] : ((i < 2048) ? bk[i - 1024] : bv[i - 2048]);
}

// ---------------- GEMM 256xBN, 8 waves (2x4), 16x16x32 MFMA, 4-phase K-tile ----------------
// R3's proven 0-conflict fragment geometry + m201-style phased schedule:
//   BN=256: ph0{issue B01; read B*,A01; 16 mfma} ph1{issue B23,Ai0; read A23; 16 mfma; vmcnt(5)}
//           ph2{issue Ai2; read A45; 16 mfma} ph3{issue Ai1,Ai3; read A67; 16 mfma; vmcnt(2)}
//   BN=128: ph0{issue B01,Ai0; read B*,A0-3; 16 mfma; vmcnt(3)} ph1{issue Ai2,Ai1,Ai3; read A4-7; 16 mfma; vmcnt(2)}
// Counted vmcnt never drains in steady state; one barrier per phase.
template<int BN, bool BIAS, bool RELU, bool RESID, bool EMB, bool WF32, bool WBF16>
__global__ __launch_bounds__(512, 2) void gemm4p(
    const unsigned short* __restrict__ A,
    const unsigned short* __restrict__ Bt,
    const float* __restrict__ bias,
    const float* __restrict__ resid,
    const float* __restrict__ pos,
    float* __restrict__ outf,
    unsigned short* __restrict__ outb,
    int M, int N, int K) {
  constexpr int NJ = BN / 64;                    // B frags per wave (4 or 2)
  constexpr int WCN = BN / 4;                    // per-wave col span
  constexpr int BUFSZ = 32768 + BN * 128;
  __shared__ __align__(1024) char smem[2 * BUFSZ];
  const int t = threadIdx.x, lane = t & 63, w = t >> 6;
  const int wr = w >> 2, wc = w & 3;             // 2x4 wave grid

  // bijective XCD swizzle (all grids divisible by 8)
  int flat = blockIdx.x + gridDim.x * blockIdx.y;
  const int cpx = (gridDim.x * gridDim.y) >> 3;
  flat = (flat & 7) * cpx + (flat >> 3);
  const int m0 = (flat / gridDim.x) * 256;
  const int n0 = (flat % gridDim.x) * BN;

  const f32x4_t z = {0.f, 0.f, 0.f, 0.f};
  f32x4_t acc[8][NJ];
#pragma unroll
  for (int i = 0; i < 8; ++i)
#pragma unroll
    for (int j = 0; j < NJ; ++j) acc[i][j] = z;

  auto stageA = [&](int i, int kt, int buf) {
    const int chunk = i * 8 + w;                 // rows [8*chunk, +8)
    const int byteoff = chunk * 1024 + lane * 16;
    const int row = byteoff >> 7;
    const int scb = (byteoff & 127) ^ ((row & 7) << 4);
    gload16((const char*)A + ((size_t)(m0 + row) * K + (kt << 6)) * 2 + scb,
            smem + buf * BUFSZ + chunk * 1024);
  };
  auto stageB = [&](int i, int kt, int buf) {
    const int chunk = i * 8 + w;
    const int byteoff = chunk * 1024 + lane * 16;
    const int row = byteoff >> 7;
    const int scb = (byteoff & 127) ^ ((row & 7) << 4);
    gload16((const char*)Bt + ((size_t)(n0 + row) * K + (kt << 6)) * 2 + scb,
            smem + buf * BUFSZ + 32768 + chunk * 1024);
  };
  auto readA = [&](const char* ab, int fi, int ks) {
    const int row = wr * 128 + fi * 16 + (lane & 15);
    const int cb = ks * 64 + ((lane >> 4) << 4);
    return *(const bf16x8_t*)(ab + row * 128 + (cb ^ ((row & 7) << 4)));
  };
  auto readB = [&](const char* bb, int j, int ks) {
    const int row = wc * WCN + j * 16 + (lane & 15);
    const int cb = ks * 64 + ((lane >> 4) << 4);
    return *(const bf16x8_t*)(bb + row * 128 + (cb ^ ((row & 7) << 4)));
  };

  // prologue: tile 0 in need-order (B*, Ai0, Ai2, Ai1, Ai3)
  stageB(0, 0, 0); stageB(1, 0, 0);
  if constexpr (BN == 256) { stageB(2, 0, 0); stageB(3, 0, 0); }
  stageA(0, 0, 0); stageA(2, 0, 0); stageA(1, 0, 0); stageA(3, 0, 0);
  vwait<2>(); bar();

  const int nkt = K >> 6;
  for (int kt = 0; kt < nkt; ++kt) {
    const char* ab = smem + (kt & 1) * BUFSZ;
    const char* bb = ab + 32768;
    const int nb = (kt & 1) ^ 1;
    const bool pf = (kt + 1 < nkt);
    bf16x8_t bfr[NJ][2], af[2][2];

    if constexpr (BN == 256) {
      // ---- ph0: B frags + A rows {0,1} ----
      if (pf) { stageB(0, kt + 1, nb); stageB(1, kt + 1, nb); }
#pragma unroll
      for (int j = 0; j < NJ; ++j)
#pragma unroll
        for (int ks = 0; ks < 2; ++ks) bfr[j][ks] = readB(bb, j, ks);
#pragma unroll
      for (int d = 0; d < 2; ++d)
#pragma unroll
        for (int ks = 0; ks < 2; ++ks) af[d][ks] = readA(ab, d, ks);
      __builtin_amdgcn_s_setprio(1);
#pragma unroll
      for (int ks = 0; ks < 2; ++ks)
#pragma unroll
        for (int d = 0; d < 2; ++d)
#pragma unroll
          for (int j = 0; j < NJ; ++j)
            acc[d][j] = __builtin_amdgcn_mfma_f32_16x16x32_bf16(af[d][ks], bfr[j][ks], acc[d][j], 0, 0, 0);
      __builtin_amdgcn_s_setprio(0);
      bar();
      // ---- ph1: A rows {2,3} ----
      if (pf) { stageB(2, kt + 1, nb); stageB(3, kt + 1, nb); stageA(0, kt + 1, nb); }
#pragma unroll
      for (int d = 0; d < 2; ++d)
#pragma unroll
        for (int ks = 0; ks < 2; ++ks) af[d][ks] = readA(ab, 2 + d, ks);
      __builtin_amdgcn_s_setprio(1);
#pragma unroll
      for (int ks = 0; ks < 2; ++ks)
#pragma unroll
        for (int d = 0; d < 2; ++d)
#pragma unroll
          for (int j = 0; j < NJ; ++j)
            acc[2 + d][j] = __builtin_amdgcn_mfma_f32_16x16x32_bf16(af[d][ks], bfr[j][ks], acc[2 + d][j], 0, 0, 0);
      __builtin_amdgcn_s_setprio(0);
      if (pf) vwait<5>(); else vwait<0>();
      bar();
      // ---- ph2: A rows {4,5} ----
      if (pf) stageA(2, kt + 1, nb);
#pragma unroll
      for (int d = 0; d < 2; ++d)
#pragma unroll
        for (int ks = 0; ks < 2; ++ks) af[d][ks] = readA(ab, 4 + d, ks);
      __builtin_amdgcn_s_setprio(1);
#pragma unroll
      for (int ks = 0; ks < 2; ++ks)
#pragma unroll
        for (int d = 0; d < 2; ++d)
#pragma unroll
          for (int j = 0; j < NJ; ++j)
            acc[4 + d][j] = __builtin_amdgcn_mfma_f32_16x16x32_bf16(af[d][ks], bfr[j][ks], acc[4 + d][j], 0, 0, 0);
      __builtin_amdgcn_s_setprio(0);
      bar();
      // ---- ph3: A rows {6,7} ----
      if (pf) { stageA(1, kt + 1, nb); stageA(3, kt + 1, nb); }
#pragma unroll
      for (int d = 0; d < 2; ++d)
#pragma unroll
        for (int ks = 0; ks < 2; ++ks) af[d][ks] = readA(ab, 6 + d, ks);
      __builtin_amdgcn_s_setprio(1);
#pragma unroll
      for (int ks = 0; ks < 2; ++ks)
#pragma unroll
        for (int d = 0; d < 2; ++d)
#pragma unroll
          for (int j = 0; j < NJ; ++j)
            acc[6 + d][j] = __builtin_amdgcn_mfma_f32_16x16x32_bf16(af[d][ks], bfr[j][ks], acc[6 + d][j], 0, 0, 0);
      __builtin_amdgcn_s_setprio(0);
      if (pf) { vwait<2>(); bar(); }
    } else {
      // ---- BN=128, ph0: B frags + A rows {0..3} ----
      bf16x8_t af4[4][2];
      if (pf) { stageB(0, kt + 1, nb); stageB(1, kt + 1, nb); stageA(0, kt + 1, nb); }
#pragma unroll
      for (int j = 0; j < NJ; ++j)
#pragma unroll
        for (int ks = 0; ks < 2; ++ks) bfr[j][ks] = readB(bb, j, ks);
#pragma unroll
      for (int d = 0; d < 4; ++d)
#pragma unroll
        for (int ks = 0; ks < 2; ++ks) af4[d][ks] = readA(ab, d, ks);
      __builtin_amdgcn_s_setprio(1);
#pragma unroll
      for (int ks = 0; ks < 2; ++ks)
#pragma unroll
        for (int d = 0; d < 4; ++d)
#pragma unroll
          for (int j = 0; j < NJ; ++j)
            acc[d][j] = __builtin_amdgcn_mfma_f32_16x16x32_bf16(af4[d][ks], bfr[j][ks], acc[d][j], 0, 0, 0);
      __builtin_amdgcn_s_setprio(0);
      if (pf) vwait<3>(); else vwait<0>();
      bar();
      // ---- ph1: A rows {4..7} ----
      if (pf) { stageA(2, kt + 1, nb); stageA(1, kt + 1, nb); stageA(3, kt + 1, nb); }
#pragma unroll
      for (int d = 0; d < 4; ++d)
#pragma unroll
        for (int ks = 0; ks < 2; ++ks) af4[d][ks] = readA(ab, 4 + d, ks);
      __builtin_amdgcn_s_setprio(1);
#pragma unroll
      for (int ks = 0; ks < 2; ++ks)
#pragma unroll
        for (int d = 0; d < 4; ++d)
#pragma unroll
          for (int j = 0; j < NJ; ++j)
            acc[4 + d][j] = __builtin_amdgcn_mfma_f32_16x16x32_bf16(af4[d][ks], bfr[j][ks], acc[4 + d][j], 0, 0, 0);
      __builtin_amdgcn_s_setprio(0);
      if (pf) { vwait<2>(); bar(); }
    }
  }

  // epilogue: C/D layout col=lane&15, row=(lane>>4)*4+r
#pragma unroll
  for (int i = 0; i < 8; ++i) {
    const int rbase = m0 + wr * 128 + i * 16 + ((lane >> 4) << 2);
#pragma unroll
    for (int j = 0; j < NJ; ++j) {
      const int cc = n0 + wc * WCN + j * 16 + (lane & 15);
      float bv = 0.f;
      if (BIAS) bv = bias[cc];
#pragma unroll
      for (int r = 0; r < 4; ++r) {
        const int row = rbase + r;
        float v = acc[i][j][r] + bv;
        if (EMB)  v = v * 32.f + pos[(size_t)(row & (SS - 1)) * N + cc];
        if (RELU) v = fmaxf(v, 0.f);
        if (RESID) v += resid[(size_t)row * N + cc];
        if (WF32)  outf[(size_t)row * N + cc] = v;
        if (WBF16) outb[(size_t)row * N + cc] = f2b(v);
      }
    }
  }
}

// ---------------- flash attention, swapped-QK^T in-register softmax ----------------
__global__ __launch_bounds__(256) void attn2(
    const unsigned short* __restrict__ qkv,   // [M][3072]: Q|K|V
    const unsigned short* __restrict__ vt,    // [bh][64][1024] = V^T per head
    unsigned short* __restrict__ O) {         // [M][1024]
  __shared__ __align__(1024) char smem[2 * 16384];   // dbuf x (K 8KB | VT 8KB)
  const int t = threadIdx.x, lane = t & 63, w = t >> 6;
  const int l31 = lane & 31, lg = lane >> 5;   // lane group (0/1)
  const int bh = blockIdx.y;
  const int b = bh >> 4, h = bh & 15;
  const size_t rowb = (size_t)b << 10;
  const int q0 = blockIdx.x * 128 + w * 32;

  bf16x8_t qf[4];
  {
    const unsigned short* Qp = qkv + (rowb + q0 + l31) * 3072 + h * 64 + lg * 8;
#pragma unroll
    for (int dd = 0; dd < 4; ++dd) qf[dd] = *(const bf16x8_t*)(Qp + dd * 16);
  }

  f32x16_t oa0, oa1;
#pragma unroll
  for (int r = 0; r < 16; ++r) { oa0[r] = 0.f; oa1[r] = 0.f; }
  float m_run = -1e30f, l_run = 0.f;
  const float inv32 = 1.f / 32.f;

  const char* kglob = (const char*)qkv + ((size_t)1024 + h * 64) * 2;
  const char* vglob = (const char*)vt + (size_t)bh * 64 * 1024 * 2;

  auto stage = [&](int kt, int buf) {
    char* kbuf = smem + buf * 16384;
    char* vbuf = kbuf + 8192;
#pragma unroll
    for (int i = 0; i < 2; ++i) {
      const int chunk = w * 2 + i;                 // 0..7
      const int byteoff = chunk * 1024 + lane * 16;
      const int row = byteoff >> 7;                // 0..63
      const int scb = (byteoff & 127) ^ ((row & 7) << 4);
      gload16(kglob + (size_t)(rowb + kt * 64 + row) * 6144 + scb, kbuf + chunk * 1024);
      gload16(vglob + ((size_t)row * 1024 + kt * 64) * 2 + scb,    vbuf + chunk * 1024);
    }
  };

  stage(0, 0);
  for (int kt = 0; kt < 16; ++kt) {
    const int cb = kt & 1;
    __syncthreads();
    if (kt < 15) stage(kt + 1, cb ^ 1);
    const char* kbuf = smem + cb * 16384;
    const char* vbuf = kbuf + 8192;

    f32x16_t p0, p1;
#pragma unroll
    for (int r = 0; r < 16; ++r) { p0[r] = 0.f; p1[r] = 0.f; }
    __builtin_amdgcn_s_setprio(1);
#pragma unroll
    for (int dd = 0; dd < 4; ++dd) {
      {
        const int row = l31;
        const int col = (dd * 32 + (lg << 4)) ^ ((row & 7) << 4);
        bf16x8_t kf = *(const bf16x8_t*)(kbuf + row * 128 + col);
        p0 = __builtin_amdgcn_mfma_f32_32x32x16_bf16(kf, qf[dd], p0, 0, 0, 0);
      }
      {
        const int row = 32 + l31;
        const int col = (dd * 32 + (lg << 4)) ^ ((row & 7) << 4);
        bf16x8_t kf = *(const bf16x8_t*)(kbuf + row * 128 + col);
        p1 = __builtin_amdgcn_mfma_f32_32x32x16_bf16(kf, qf[dd], p1, 0, 0, 0);
      }
    }
    __builtin_amdgcn_s_setprio(0);

    float mx = p0[0];
#pragma unroll
    for (int r = 1; r < 16; ++r) mx = fmaxf(mx, p0[r]);
#pragma unroll
    for (int r = 0; r < 16; ++r) mx = fmaxf(mx, p1[r]);
    mx = fmaxf(mx, __shfl_xor(mx, 32));
    const float mn = fmaxf(m_run, mx * inv32);
    const float fr = __expf(m_run - mn);
    m_run = mn;
    float sum = 0.f;
#pragma unroll
    for (int r = 0; r < 16; ++r) { const float e = __expf(p0[r] * inv32 - mn); p0[r] = e; sum += e; }
#pragma unroll
    for (int r = 0; r < 16; ++r) { const float e = __expf(p1[r] * inv32 - mn); p1[r] = e; sum += e; }
    sum += __shfl_xor(sum, 32);
    l_run = l_run * fr + sum;
#pragma unroll
    for (int r = 0; r < 16; ++r) { oa0[r] *= fr; oa1[r] *= fr; }

    const unsigned A0 = pkbf(p0[0], p0[1]),  B0 = pkbf(p0[2], p0[3]);
    const unsigned C0 = pkbf(p0[4], p0[5]),  D0 = pkbf(p0[6], p0[7]);
    const unsigned E0 = pkbf(p0[8], p0[9]),  F0 = pkbf(p0[10], p0[11]);
    const unsigned G0 = pkbf(p0[12], p0[13]), H0 = pkbf(p0[14], p0[15]);
    const unsigned A1 = pkbf(p1[0], p1[1]),  B1 = pkbf(p1[2], p1[3]);
    const unsigned C1 = pkbf(p1[4], p1[5]),  D1 = pkbf(p1[6], p1[7]);
    const unsigned E1 = pkbf(p1[8], p1[9]),  F1 = pkbf(p1[10], p1[11]);
    const unsigned G1 = pkbf(p1[12], p1[13]), H1 = pkbf(p1[14], p1[15]);
    const unsigned sA0 = __shfl_xor((int)A0, 32), sB0 = __shfl_xor((int)B0, 32);
    const unsigned sC0 = __shfl_xor((int)C0, 32), sD0 = __shfl_xor((int)D0, 32);
    const unsigned sE0 = __shfl_xor((int)E0, 32), sF0 = __shfl_xor((int)F0, 32);
    const unsigned sG0 = __shfl_xor((int)G0, 32), sH0 = __shfl_xor((int)H0, 32);
    const unsigned sA1 = __shfl_xor((int)A1, 32), sB1 = __shfl_xor((int)B1, 32);
    const unsigned sC1 = __shfl_xor((int)C1, 32), sD1 = __shfl_xor((int)D1, 32);
    const unsigned sE1 = __shfl_xor((int)E1, 32), sF1 = __shfl_xor((int)F1, 32);
    const unsigned sG1 = __shfl_xor((int)G1, 32), sH1 = __shfl_xor((int)H1, 32);
    const bool hi = (lg != 0);
    bf16x8_t pf[4];
    pf[0] = hi ? mk8(sC0, sD0, C0, D0) : mk8(A0, B0, sA0, sB0);
    pf[1] = hi ? mk8(sG0, sH0, G0, H0) : mk8(E0, F0, sE0, sF0);
    pf[2] = hi ? mk8(sC1, sD1, C1, D1) : mk8(A1, B1, sA1, sB1);
    pf[3] = hi ? mk8(sG1, sH1, G1, H1) : mk8(E1, F1, sE1, sF1);

    __builtin_amdgcn_s_setprio(1);
#pragma unroll
    for (int c = 0; c < 4; ++c) {
      {
        const int row = l31;
        const int col = (c * 32 + (lg << 4)) ^ ((row & 7) << 4);
        bf16x8_t vf = *(const bf16x8_t*)(vbuf + row * 128 + col);
        oa0 = __builtin_amdgcn_mfma_f32_32x32x16_bf16(vf, pf[c], oa0, 0, 0, 0);
      }
      {
        const int row = 32 + l31;
        const int col = (c * 32 + (lg << 4)) ^ ((row & 7) << 4);
        bf16x8_t vf = *(const bf16x8_t*)(vbuf + row * 128 + col);
        oa1 = __builtin_amdgcn_mfma_f32_32x32x16_bf16(vf, pf[c], oa1, 0, 0, 0);
      }
    }
    __builtin_amdgcn_s_setprio(0);
  }

  const float inv = 1.f / l_run;
  unsigned short* op = O + (rowb + q0 + l31) * 1024 + h * 64 + (lg << 2);
#pragma unroll
  for (int rg = 0; rg < 4; ++rg) {
    const unsigned u0 = pkbf(oa0[rg * 4 + 0] * inv, oa0[rg * 4 + 1] * inv);
    const unsigned u1 = pkbf(oa0[rg * 4 + 2] * inv, oa0[rg * 4 + 3] * inv);
    uint2 st = { u0, u1 };
    *(uint2*)(op + rg * 8) = st;
    const unsigned v0 = pkbf(oa1[rg * 4 + 0] * inv, oa1[rg * 4 + 1] * inv);
    const unsigned v1 = pkbf(oa1[rg * 4 + 2] * inv, oa1[rg * 4 + 3] * inv);
    uint2 st2 = { v0, v1 };
    *(uint2*)(op + 32 + rg * 8) = st2;
  }
}

// ---------------- LayerNorm: fp32 in -> fp32 + bf16 out ----------------
__global__ __launch_bounds__(256) void ln_kernel(
    const float* __restrict__ y, const float* __restrict__ g, const float* __restrict__ be,
    float* __restrict__ xf, unsigned short* __restrict__ xb) {
  const int row = blockIdx.x;
  const int t = threadIdx.x;
  const float4 v = ((const float4*)(y + (size_t)row * HDIM))[t];
  float s  = v.x + v.y + v.z + v.w;
  float ss = v.x*v.x + v.y*v.y + v.z*v.z + v.w*v.w;
#pragma unroll
  for (int m = 1; m < 64; m <<= 1) { s += __shfl_xor(s, m); ss += __shfl_xor(ss, m); }
  __shared__ float rs[4], rss[4];
  const int w = t >> 6, lane = t & 63;
  if (lane == 0) { rs[w] = s; rss[w] = ss; }
  __syncthreads();
  s  = rs[0] + rs[1] + rs[2] + rs[3];
  ss = rss[0] + rss[1] + rss[2] + rss[3];
  const float mean = s * (1.f / HDIM);
  const float inv = rsqrtf(ss * (1.f / HDIM) - mean * mean + 1e-5f);
  const int c = t * 4;
  const float4 gg = *(const float4*)(g + c);
  const float4 bb = *(const float4*)(be + c);
  float4 o;
  o.x = (v.x - mean) * inv * gg.x + bb.x;
  o.y = (v.y - mean) * inv * gg.y + bb.y;
  o.z = (v.z - mean) * inv * gg.z + bb.z;
  o.w = (v.w - mean) * inv * gg.w + bb.w;
  ((float4*)(xf + (size_t)row * HDIM))[t] = o;
  ushort4 ob = { f2b(o.x), f2b(o.y), f2b(o.z), f2b(o.w) };
  ((ushort4*)(xb + (size_t)row * HDIM))[t] = ob;
}

// ---------------- host ----------------
extern "C" void kernel_launch(void* const* d_in, const int* in_sizes, int n_in,
                              void* d_out, int out_size, void* d_ws, size_t ws_size,
                              hipStream_t stream) {
  const float* input_x = (const float*)d_in[0];
  const float* emb_W   = (const float*)d_in[1];
  const float* emb_b   = (const float*)d_in[2];
  const float* pos_tab = (const float*)d_in[3];
  const float* Wq  = (const float*)d_in[4];
  const float* bq  = (const float*)d_in[5];
  const float* Wk  = (const float*)d_in[6];
  const float* bk  = (const float*)d_in[7];
  const float* Wv  = (const float*)d_in[8];
  const float* bv  = (const float*)d_in[9];
  const float* Wo  = (const float*)d_in[10];
  const float* bo  = (const float*)d_in[11];
  const float* ln1g = (const float*)d_in[12];
  const float* ln1b = (const float*)d_in[13];
  const float* W1  = (const float*)d_in[14];
  const float* b1  = (const float*)d_in[15];
  const float* W2  = (const float*)d_in[16];
  const float* b2  = (const float*)d_in[17];
  const float* ln2g = (const float*)d_in[18];
  const float* ln2b = (const float*)d_in[19];
  float* out = (float*)d_out;

  char* ws = (char*)d_ws;
  size_t off = 0;
  auto alloc = [&](size_t bytes) {
    char* p = ws + off;
    off += (bytes + 255) & ~(size_t)255;
    return p;
  };
  unsigned short* wqkvT = (unsigned short*)alloc((size_t)3072 * HDIM * 2);
  unsigned short* woT   = (unsigned short*)alloc((size_t)HDIM * HDIM * 2);
  unsigned short* w1T   = (unsigned short*)alloc((size_t)PFF * HDIM * 2);   // [PF][H]
  unsigned short* w2T   = (unsigned short*)alloc((size_t)HDIM * PFF * 2);   // [H][PF]
  unsigned short* embWT = (unsigned short*)alloc((size_t)HDIM * 256 * 2);   // [H][IN]
  float*          bqkv  = (float*)alloc(3072 * 4);
  unsigned short* inb   = (unsigned short*)alloc((size_t)MM * 256 * 2);
  unsigned short* xb    = (unsigned short*)alloc((size_t)MM * HDIM * 2);
  unsigned short* qkvb  = (unsigned short*)alloc((size_t)MM * 3072 * 2);    // 48MB
  unsigned short* vtb   = (unsigned short*)alloc((size_t)MM * HDIM * 2);    // 16MB
  unsigned short* ab    = (unsigned short*)alloc((size_t)MM * HDIM * 2);
  float* y = (float*)alloc((size_t)MM * HDIM * 4);
  unsigned short* hb = qkvb;   // FFN hidden [M][4096] spans qkvb+vtb (dead by FFN1)

  const dim3 blk256(256);
  const dim3 blk512(512);
  const dim3 tblk(32, 8);

  // prep
  cvt_bf16<<<dim3(MM * 256 / 4 / 256), blk256, 0, stream>>>(input_x, inb, MM * 256 / 4);
  transpose_bf16<<<dim3(HDIM / 32, 256 / 32), tblk, 0, stream>>>(emb_W, embWT, 256, HDIM);

  // embedding: x = (input @ embW + b)*32 + pos   -> out(fp32) + xb(bf16)
  gemm4p<128, true, false, false, true, true, true><<<dim3(HDIM / 128, MM / 256), blk512, 0, stream>>>(
      inb, embWT, emb_b, nullptr, pos_tab, out, xb, MM, HDIM, 256);

  for (int l = 0; l < NLAYER; ++l) {
    const size_t wofs = (size_t)l * HDIM * HDIM;
    transpose_bf16<<<dim3(32, 32), tblk, 0, stream>>>(Wq + wofs, wqkvT,               HDIM, HDIM);
    transpose_bf16<<<dim3(32, 32), tblk, 0, stream>>>(Wk + wofs, wqkvT + 1024 * 1024, HDIM, HDIM);
    transpose_bf16<<<dim3(32, 32), tblk, 0, stream>>>(Wv + wofs, wqkvT + 2048 * 1024, HDIM, HDIM);
    transpose_bf16<<<dim3(32, 32), tblk, 0, stream>>>(Wo + wofs, woT, HDIM, HDIM);
    transpose_bf16<<<dim3(PFF / 32, HDIM / 32), tblk, 0, stream>>>(
        W1 + (size_t)l * HDIM * PFF, w1T, HDIM, PFF);
    transpose_bf16<<<dim3(HDIM / 32, PFF / 32), tblk, 0, stream>>>(
        W2 + (size_t)l * PFF * HDIM, w2T, PFF, HDIM);
    concat_bias<<<dim3(12), blk256, 0, stream>>>(bq + l * HDIM, bk + l * HDIM, bv + l * HDIM, bqkv);

    // fused QKV GEMM -> qkvb [M][3072]
    gemm4p<256, true, false, false, false, false, true><<<dim3(3072 / 256, MM / 256), blk512, 0, stream>>>(
        xb, wqkvT, bqkv, nullptr, nullptr, nullptr, qkvb, MM, 3072, HDIM);

    // V^T per head
    vtrans<<<dim3(32, 256), tblk, 0, stream>>>(qkvb, vtb);

    // attention
    attn2<<<dim3(SS / 128, BB * NHEAD), blk256, 0, stream>>>(qkvb, vtb, ab);

    // O-proj + residual (resid = fp32 x in `out`)
    gemm4p<128, true, false, true, false, true, false><<<dim3(HDIM / 128, MM / 256), blk512, 0, stream>>>(
        ab, woT, bo + l * HDIM, out, nullptr, y, nullptr, MM, HDIM, HDIM);
    ln_kernel<<<dim3(MM), blk256, 0, stream>>>(y, ln1g + l * HDIM, ln1b + l * HDIM, out, xb);

    // FFN
    gemm4p<256, true, true, false, false, false, true><<<dim3(PFF / 256, MM / 256), blk512, 0, stream>>>(
        xb, w1T, b1 + (size_t)l * PFF, nullptr, nullptr, nullptr, hb, MM, PFF, HDIM);
    gemm4p<128, true, false, true, false, true, false><<<dim3(HDIM / 128, MM / 256), blk512, 0, stream>>>(
        hb, w2T, b2 + l * HDIM, out, nullptr, y, nullptr, MM, HDIM, PFF);
    ln_kernel<<<dim3(MM), blk256, 0, stream>>>(y, ln2g + l * HDIM, ln2b + l * HDIM, out, xb);
  }
  (void)in_sizes; (void)n_in; (void)out_size; (void)ws_size;
}

// Round 6
// 2219.016 us; speedup vs baseline: 1.0341x; 1.0090x over previous
//
#include <hip/hip_runtime.h>

// ---------------- constants ----------------
#define HDIM 1024
#define BB 8
#define SS 1024
#define NHEAD 16
#define PFF 4096
#define NLAYER 6
#define MM (BB*SS)   // 8192 rows

typedef __attribute__((ext_vector_type(8))) short bf16x8_t;
typedef __attribute__((ext_vector_type(4))) float f32x4_t;
typedef __attribute__((ext_vector_type(16))) float f32x16_t;

static __device__ __forceinline__ unsigned short f2b(float f) {
  unsigned int u = __float_as_uint(f);
  u += 0x7fffu + ((u >> 16) & 1u);      // RNE
  return (unsigned short)(u >> 16);
}

static __device__ __forceinline__ unsigned pkbf(float lo, float hi) {
  unsigned r;
  asm("v_cvt_pk_bf16_f32 %0, %1, %2" : "=v"(r) : "v"(lo), "v"(hi));
  return r;
}

static __device__ __forceinline__ bf16x8_t mk8(unsigned a, unsigned b, unsigned c, unsigned d) {
  union { unsigned u[4]; bf16x8_t v; } x;
  x.u[0] = a; x.u[1] = b; x.u[2] = c; x.u[3] = d;
  return x.v;
}

static __device__ __forceinline__ void gload16(const void* g, void* l) {
  __builtin_amdgcn_global_load_lds((__attribute__((address_space(1))) void*)g,
                                   (__attribute__((address_space(3))) void*)l, 16, 0, 0);
}

template<int N>
static __device__ __forceinline__ void vwait() {
  asm volatile("s_waitcnt vmcnt(%0)" :: "n"(N) : "memory");
}

static __device__ __forceinline__ void bar() {
  asm volatile("" ::: "memory");
  __builtin_amdgcn_s_barrier();
  asm volatile("" ::: "memory");
}

// ---------------- fp32 -> bf16 convert ----------------
__global__ __launch_bounds__(256) void cvt_bf16(const float* __restrict__ in,
                                                unsigned short* __restrict__ o, int n4) {
  const int i = blockIdx.x * 256 + threadIdx.x;
  if (i < n4) {
    const float4 v = ((const float4*)in)[i];
    ushort4 ob = { f2b(v.x), f2b(v.y), f2b(v.z), f2b(v.w) };
    ((ushort4*)o)[i] = ob;
  }
}

// ---------------- transpose fp32 [R][C] -> bf16 [C][R] ----------------
__global__ __launch_bounds__(256) void transpose_bf16(const float* __restrict__ in,
                                                      unsigned short* __restrict__ outT,
                                                      int R, int C) {
  __shared__ float tile[32][33];
  const int c0 = blockIdx.x * 32, r0 = blockIdx.y * 32;
  const int tx = threadIdx.x, ty = threadIdx.y;   // (32,8)
#pragma unroll
  for (int i = 0; i < 4; ++i)
    tile[ty + 8*i][tx] = in[(size_t)(r0 + ty + 8*i) * C + c0 + tx];
  __syncthreads();
#pragma unroll
  for (int i = 0; i < 4; ++i)
    outT[(size_t)(c0 + ty + 8*i) * R + r0 + tx] = f2b(tile[tx][ty + 8*i]);
}

// ---------------- V^T extraction: qkv[M][3072] (V at col 2048+) -> vt[bh][64][1024] ----------------
__global__ __launch_bounds__(256) void vtrans(const unsigned short* __restrict__ qkv,
                                              unsigned short* __restrict__ vt) {
  __shared__ unsigned short tile[32][34];
  const int s0 = blockIdx.x * 32;
  const int by = blockIdx.y;           // bh*2 + dt
  const int bh = by >> 1, dt = by & 1;
  const int b = bh >> 4, h = bh & 15;
  const int tx = threadIdx.x, ty = threadIdx.y;  // (32,8)
  const unsigned short* src = qkv + ((size_t)(b * 1024 + s0)) * 3072 + 2048 + h * 64 + dt * 32;
#pragma unroll
  for (int i = 0; i < 4; ++i)
    tile[ty + 8*i][tx] = src[(size_t)(ty + 8*i) * 3072 + tx];
  __syncthreads();
  unsigned short* dst = vt + (size_t)(bh * 64 + dt * 32) * 1024 + s0;
#pragma unroll
  for (int i = 0; i < 4; ++i)
    dst[(size_t)(ty + 8*i) * 1024 + tx] = tile[tx][ty + 8*i];
}

// ---------------- bias concat for fused QKV ----------------
__global__ __launch_bounds__(256) void concat_bias(const float* __restrict__ bq,
                                                   const float* __restrict__ bk,
                                                   const float* __restrict__ bv,
                                                   float* __restrict__ o) {
  const int i = blockIdx.x * 256 + threadIdx.x;   // 0..3071
  o[i] = (i < 1024) ? bq[i] : ((i < 2048) ? bk[i - 1024] : bv[i - 2048]);
}

// ---------------- GEMM 256xBN, 8 waves (2x4), 16x16x32, pipelined 2-barrier K-tile ----------------
// ds_reads for phase p+1 are issued during phase p's MFMA cluster; every cluster
// after ph0 starts with fragments resident. 2 barriers + 2 counted vmcnt per tile.
// Issue order per tile: g0=[B0,B1] g1=[B2,B3,A0] g2=[A2] g3=[A1,A3].
// A-band map: frags0-3 -> bands A0/A2 (certified at tile-start vmcnt(2));
//             frags4-7 -> bands A1/A3 (certified at ph1 vmcnt(2) / BN128 vmcnt(3)).
template<int BN, bool BIAS, bool RELU, bool RESID, bool EMB, bool WF32, bool WBF16>
__global__ __launch_bounds__(512, 2) void gemm2b(
    const unsigned short* __restrict__ A,
    const unsigned short* __restrict__ Bt,
    const float* __restrict__ bias,
    const float* __restrict__ resid,
    const float* __restrict__ pos,
    float* __restrict__ outf,
    unsigned short* __restrict__ outb,
    int M, int N, int K) {
  constexpr int NJ = BN / 64;                    // B frags per wave (4 or 2)
  constexpr int WCN = BN / 4;                    // per-wave col span
  constexpr int BUFSZ = 32768 + BN * 128;
  __shared__ __align__(1024) char smem[2 * BUFSZ];
  const int t = threadIdx.x, lane = t & 63, w = t >> 6;
  const int wr = w >> 2, wc = w & 3;             // 2x4 wave grid

  // bijective XCD swizzle (all grids divisible by 8)
  int flat = blockIdx.x + gridDim.x * blockIdx.y;
  const int cpx = (gridDim.x * gridDim.y) >> 3;
  flat = (flat & 7) * cpx + (flat >> 3);
  const int m0 = (flat / gridDim.x) * 256;
  const int n0 = (flat % gridDim.x) * BN;

  const f32x4_t z = {0.f, 0.f, 0.f, 0.f};
  f32x4_t acc[8][NJ];
#pragma unroll
  for (int i = 0; i < 8; ++i)
#pragma unroll
    for (int j = 0; j < NJ; ++j) acc[i][j] = z;

  auto stageA = [&](int i, int kt, int buf) {
    const int chunk = i * 8 + w;                 // band i = rows [64*i, +64)
    const int byteoff = chunk * 1024 + lane * 16;
    const int row = byteoff >> 7;
    const int scb = (byteoff & 127) ^ ((row & 7) << 4);
    gload16((const char*)A + ((size_t)(m0 + row) * K + (kt << 6)) * 2 + scb,
            smem + buf * BUFSZ + chunk * 1024);
  };
  auto stageB = [&](int i, int kt, int buf) {
    const int chunk = i * 8 + w;
    const int byteoff = chunk * 1024 + lane * 16;
    const int row = byteoff >> 7;
    const int scb = (byteoff & 127) ^ ((row & 7) << 4);
    gload16((const char*)Bt + ((size_t)(n0 + row) * K + (kt << 6)) * 2 + scb,
            smem + buf * BUFSZ + 32768 + chunk * 1024);
  };
  auto readA = [&](const char* ab, int fi, int ks) {
    const int row = wr * 128 + fi * 16 + (lane & 15);
    const int cb = ks * 64 + ((lane >> 4) << 4);
    return *(const bf16x8_t*)(ab + row * 128 + (cb ^ ((row & 7) << 4)));
  };
  auto readB = [&](const char* bb, int j, int ks) {
    const int row = wc * WCN + j * 16 + (lane & 15);
    const int cb = ks * 64 + ((lane >> 4) << 4);
    return *(const bf16x8_t*)(bb + row * 128 + (cb ^ ((row & 7) << 4)));
  };

  // prologue: tile 0, need-order, A1/A3 last
  stageB(0, 0, 0); stageB(1, 0, 0);
  if constexpr (BN == 256) { stageB(2, 0, 0); stageB(3, 0, 0); }
  stageA(0, 0, 0); stageA(2, 0, 0); stageA(1, 0, 0); stageA(3, 0, 0);

  const int nkt = K >> 6;
  for (int kt = 0; kt < nkt; ++kt) {
    const char* ab = smem + (kt & 1) * BUFSZ;
    const char* bb = ab + 32768;
    const int nb = (kt & 1) ^ 1;
    const bool pf = (kt + 1 < nkt);
    bf16x8_t bfr[NJ][2], af[8][2];

    if constexpr (BN == 256) {
      // ---- ph0: certify {B*,A0,A2}; read B + frags0-3; MFMA 0-1 ----
      vwait<2>(); bar();
      if (pf) { stageB(0, kt + 1, nb); stageB(1, kt + 1, nb); }
#pragma unroll
      for (int j = 0; j < NJ; ++j)
#pragma unroll
        for (int ks = 0; ks < 2; ++ks) bfr[j][ks] = readB(bb, j, ks);
#pragma unroll
      for (int d = 0; d < 4; ++d)
#pragma unroll
        for (int ks = 0; ks < 2; ++ks) af[d][ks] = readA(ab, d, ks);
      __builtin_amdgcn_s_setprio(1);
#pragma unroll
      for (int ks = 0; ks < 2; ++ks)
#pragma unroll
        for (int d = 0; d < 2; ++d)
#pragma unroll
          for (int j = 0; j < NJ; ++j)
            acc[d][j] = __builtin_amdgcn_mfma_f32_16x16x32_bf16(af[d][ks], bfr[j][ks], acc[d][j], 0, 0, 0);
      __builtin_amdgcn_s_setprio(0);
      // ---- ph1: certify {A1,A3}; read frags4-5; MFMA 2-3 ----
      if (pf) vwait<2>(); else vwait<0>();
      bar();
      if (pf) { stageB(2, kt + 1, nb); stageB(3, kt + 1, nb); stageA(0, kt + 1, nb); }
#pragma unroll
      for (int d = 4; d < 6; ++d)
#pragma unroll
        for (int ks = 0; ks < 2; ++ks) af[d][ks] = readA(ab, d, ks);
      __builtin_amdgcn_s_setprio(1);
#pragma unroll
      for (int ks = 0; ks < 2; ++ks)
#pragma unroll
        for (int d = 2; d < 4; ++d)
#pragma unroll
          for (int j = 0; j < NJ; ++j)
            acc[d][j] = __builtin_amdgcn_mfma_f32_16x16x32_bf16(af[d][ks], bfr[j][ks], acc[d][j], 0, 0, 0);
      __builtin_amdgcn_s_setprio(0);
      // ---- ph2: read frags6-7; MFMA 4-5 ----
      if (pf) stageA(2, kt + 1, nb);
#pragma unroll
      for (int d = 6; d < 8; ++d)
#pragma unroll
        for (int ks = 0; ks < 2; ++ks) af[d][ks] = readA(ab, d, ks);
      __builtin_amdgcn_s_setprio(1);
#pragma unroll
      for (int ks = 0; ks < 2; ++ks)
#pragma unroll
        for (int d = 4; d < 6; ++d)
#pragma unroll
          for (int j = 0; j < NJ; ++j)
            acc[d][j] = __builtin_amdgcn_mfma_f32_16x16x32_bf16(af[d][ks], bfr[j][ks], acc[d][j], 0, 0, 0);
      __builtin_amdgcn_s_setprio(0);
      // ---- ph3: MFMA 6-7 (frags resident) ----
      if (pf) { stageA(1, kt + 1, nb); stageA(3, kt + 1, nb); }
      __builtin_amdgcn_s_setprio(1);
#pragma unroll
      for (int ks = 0; ks < 2; ++ks)
#pragma unroll
        for (int d = 6; d < 8; ++d)
#pragma unroll
          for (int j = 0; j < NJ; ++j)
            acc[d][j] = __builtin_amdgcn_mfma_f32_16x16x32_bf16(af[d][ks], bfr[j][ks], acc[d][j], 0, 0, 0);
      __builtin_amdgcn_s_setprio(0);
    } else {
      // ---- BN=128, ph0: certify {B*,A0,A2}; read B + frags0-3; MFMA 0-3 ----
      vwait<2>(); bar();
      if (pf) { stageB(0, kt + 1, nb); stageB(1, kt + 1, nb); stageA(0, kt + 1, nb); }
#pragma unroll
      for (int j = 0; j < NJ; ++j)
#pragma unroll
        for (int ks = 0; ks < 2; ++ks) bfr[j][ks] = readB(bb, j, ks);
#pragma unroll
      for (int d = 0; d < 4; ++d)
#pragma unroll
        for (int ks = 0; ks < 2; ++ks) af[d][ks] = readA(ab, d, ks);
      __builtin_amdgcn_s_setprio(1);
#pragma unroll
      for (int ks = 0; ks < 2; ++ks)
#pragma unroll
        for (int d = 0; d < 4; ++d)
#pragma unroll
          for (int j = 0; j < NJ; ++j)
            acc[d][j] = __builtin_amdgcn_mfma_f32_16x16x32_bf16(af[d][ks], bfr[j][ks], acc[d][j], 0, 0, 0);
      __builtin_amdgcn_s_setprio(0);
      // ---- ph1: certify {A1,A3}; read frags4-7; MFMA 4-7 ----
      if (pf) vwait<3>(); else vwait<0>();
      bar();
      if (pf) { stageA(2, kt + 1, nb); stageA(1, kt + 1, nb); stageA(3, kt + 1, nb); }
#pragma unroll
      for (int d = 4; d < 8; ++d)
#pragma unroll
        for (int ks = 0; ks < 2; ++ks) af[d][ks] = readA(ab, d, ks);
      __builtin_amdgcn_s_setprio(1);
#pragma unroll
      for (int ks = 0; ks < 2; ++ks)
#pragma unroll
        for (int d = 4; d < 8; ++d)
#pragma unroll
          for (int j = 0; j < NJ; ++j)
            acc[d][j] = __builtin_amdgcn_mfma_f32_16x16x32_bf16(af[d][ks], bfr[j][ks], acc[d][j], 0, 0, 0);
      __builtin_amdgcn_s_setprio(0);
    }
  }

  // epilogue: C/D layout col=lane&15, row=(lane>>4)*4+r
#pragma unroll
  for (int i = 0; i < 8; ++i) {
    const int rbase = m0 + wr * 128 + i * 16 + ((lane >> 4) << 2);
#pragma unroll
    for (int j = 0; j < NJ; ++j) {
      const int cc = n0 + wc * WCN + j * 16 + (lane & 15);
      float bv = 0.f;
      if (BIAS) bv = bias[cc];
#pragma unroll
      for (int r = 0; r < 4; ++r) {
        const int row = rbase + r;
        float v = acc[i][j][r] + bv;
        if (EMB)  v = v * 32.f + pos[(size_t)(row & (SS - 1)) * N + cc];
        if (RELU) v = fmaxf(v, 0.f);
        if (RESID) v += resid[(size_t)row * N + cc];
        if (WF32)  outf[(size_t)row * N + cc] = v;
        if (WBF16) outb[(size_t)row * N + cc] = f2b(v);
      }
    }
  }
}

// ---------------- flash attention, swapped-QK^T in-register softmax ----------------
__global__ __launch_bounds__(256) void attn2(
    const unsigned short* __restrict__ qkv,   // [M][3072]: Q|K|V
    const unsigned short* __restrict__ vt,    // [bh][64][1024] = V^T per head
    unsigned short* __restrict__ O) {         // [M][1024]
  __shared__ __align__(1024) char smem[2 * 16384];   // dbuf x (K 8KB | VT 8KB)
  const int t = threadIdx.x, lane = t & 63, w = t >> 6;
  const int l31 = lane & 31, lg = lane >> 5;   // lane group (0/1)
  const int bh = blockIdx.y;
  const int b = bh >> 4, h = bh & 15;
  const size_t rowb = (size_t)b << 10;
  const int q0 = blockIdx.x * 128 + w * 32;

  bf16x8_t qf[4];
  {
    const unsigned short* Qp = qkv + (rowb + q0 + l31) * 3072 + h * 64 + lg * 8;
#pragma unroll
    for (int dd = 0; dd < 4; ++dd) qf[dd] = *(const bf16x8_t*)(Qp + dd * 16);
  }

  f32x16_t oa0, oa1;
#pragma unroll
  for (int r = 0; r < 16; ++r) { oa0[r] = 0.f; oa1[r] = 0.f; }
  float m_run = -1e30f, l_run = 0.f;
  const float inv32 = 1.f / 32.f;

  const char* kglob = (const char*)qkv + ((size_t)1024 + h * 64) * 2;
  const char* vglob = (const char*)vt + (size_t)bh * 64 * 1024 * 2;

  auto stage = [&](int kt, int buf) {
    char* kbuf = smem + buf * 16384;
    char* vbuf = kbuf + 8192;
#pragma unroll
    for (int i = 0; i < 2; ++i) {
      const int chunk = w * 2 + i;                 // 0..7
      const int byteoff = chunk * 1024 + lane * 16;
      const int row = byteoff >> 7;                // 0..63
      const int scb = (byteoff & 127) ^ ((row & 7) << 4);
      gload16(kglob + (size_t)(rowb + kt * 64 + row) * 6144 + scb, kbuf + chunk * 1024);
      gload16(vglob + ((size_t)row * 1024 + kt * 64) * 2 + scb,    vbuf + chunk * 1024);
    }
  };

  stage(0, 0);
  for (int kt = 0; kt < 16; ++kt) {
    const int cb = kt & 1;
    __syncthreads();
    if (kt < 15) stage(kt + 1, cb ^ 1);
    const char* kbuf = smem + cb * 16384;
    const char* vbuf = kbuf + 8192;

    f32x16_t p0, p1;
#pragma unroll
    for (int r = 0; r < 16; ++r) { p0[r] = 0.f; p1[r] = 0.f; }
    __builtin_amdgcn_s_setprio(1);
#pragma unroll
    for (int dd = 0; dd < 4; ++dd) {
      {
        const int row = l31;
        const int col = (dd * 32 + (lg << 4)) ^ ((row & 7) << 4);
        bf16x8_t kf = *(const bf16x8_t*)(kbuf + row * 128 + col);
        p0 = __builtin_amdgcn_mfma_f32_32x32x16_bf16(kf, qf[dd], p0, 0, 0, 0);
      }
      {
        const int row = 32 + l31;
        const int col = (dd * 32 + (lg << 4)) ^ ((row & 7) << 4);
        bf16x8_t kf = *(const bf16x8_t*)(kbuf + row * 128 + col);
        p1 = __builtin_amdgcn_mfma_f32_32x32x16_bf16(kf, qf[dd], p1, 0, 0, 0);
      }
    }
    __builtin_amdgcn_s_setprio(0);

    float mx = p0[0];
#pragma unroll
    for (int r = 1; r < 16; ++r) mx = fmaxf(mx, p0[r]);
#pragma unroll
    for (int r = 0; r < 16; ++r) mx = fmaxf(mx, p1[r]);
    mx = fmaxf(mx, __shfl_xor(mx, 32));
    const float mn = fmaxf(m_run, mx * inv32);
    const float fr = __expf(m_run - mn);
    m_run = mn;
    float sum = 0.f;
#pragma unroll
    for (int r = 0; r < 16; ++r) { const float e = __expf(p0[r] * inv32 - mn); p0[r] = e; sum += e; }
#pragma unroll
    for (int r = 0; r < 16; ++r) { const float e = __expf(p1[r] * inv32 - mn); p1[r] = e; sum += e; }
    sum += __shfl_xor(sum, 32);
    l_run = l_run * fr + sum;
#pragma unroll
    for (int r = 0; r < 16; ++r) { oa0[r] *= fr; oa1[r] *= fr; }

    const unsigned A0 = pkbf(p0[0], p0[1]),  B0 = pkbf(p0[2], p0[3]);
    const unsigned C0 = pkbf(p0[4], p0[5]),  D0 = pkbf(p0[6], p0[7]);
    const unsigned E0 = pkbf(p0[8], p0[9]),  F0 = pkbf(p0[10], p0[11]);
    const unsigned G0 = pkbf(p0[12], p0[13]), H0 = pkbf(p0[14], p0[15]);
    const unsigned A1 = pkbf(p1[0], p1[1]),  B1 = pkbf(p1[2], p1[3]);
    const unsigned C1 = pkbf(p1[4], p1[5]),  D1 = pkbf(p1[6], p1[7]);
    const unsigned E1 = pkbf(p1[8], p1[9]),  F1 = pkbf(p1[10], p1[11]);
    const unsigned G1 = pkbf(p1[12], p1[13]), H1 = pkbf(p1[14], p1[15]);
    const unsigned sA0 = __shfl_xor((int)A0, 32), sB0 = __shfl_xor((int)B0, 32);
    const unsigned sC0 = __shfl_xor((int)C0, 32), sD0 = __shfl_xor((int)D0, 32);
    const unsigned sE0 = __shfl_xor((int)E0, 32), sF0 = __shfl_xor((int)F0, 32);
    const unsigned sG0 = __shfl_xor((int)G0, 32), sH0 = __shfl_xor((int)H0, 32);
    const unsigned sA1 = __shfl_xor((int)A1, 32), sB1 = __shfl_xor((int)B1, 32);
    const unsigned sC1 = __shfl_xor((int)C1, 32), sD1 = __shfl_xor((int)D1, 32);
    const unsigned sE1 = __shfl_xor((int)E1, 32), sF1 = __shfl_xor((int)F1, 32);
    const unsigned sG1 = __shfl_xor((int)G1, 32), sH1 = __shfl_xor((int)H1, 32);
    const bool hi = (lg != 0);
    bf16x8_t pf[4];
    pf[0] = hi ? mk8(sC0, sD0, C0, D0) : mk8(A0, B0, sA0, sB0);
    pf[1] = hi ? mk8(sG0, sH0, G0, H0) : mk8(E0, F0, sE0, sF0);
    pf[2] = hi ? mk8(sC1, sD1, C1, D1) : mk8(A1, B1, sA1, sB1);
    pf[3] = hi ? mk8(sG1, sH1, G1, H1) : mk8(E1, F1, sE1, sF1);

    __builtin_amdgcn_s_setprio(1);
#pragma unroll
    for (int c = 0; c < 4; ++c) {
      {
        const int row = l31;
        const int col = (c * 32 + (lg << 4)) ^ ((row & 7) << 4);
        bf16x8_t vf = *(const bf16x8_t*)(vbuf + row * 128 + col);
        oa0 = __builtin_amdgcn_mfma_f32_32x32x16_bf16(vf, pf[c], oa0, 0, 0, 0);
      }
      {
        const int row = 32 + l31;
        const int col = (c * 32 + (lg << 4)) ^ ((row & 7) << 4);
        bf16x8_t vf = *(const bf16x8_t*)(vbuf + row * 128 + col);
        oa1 = __builtin_amdgcn_mfma_f32_32x32x16_bf16(vf, pf[c], oa1, 0, 0, 0);
      }
    }
    __builtin_amdgcn_s_setprio(0);
  }

  const float inv = 1.f / l_run;
  unsigned short* op = O + (rowb + q0 + l31) * 1024 + h * 64 + (lg << 2);
#pragma unroll
  for (int rg = 0; rg < 4; ++rg) {
    const unsigned u0 = pkbf(oa0[rg * 4 + 0] * inv, oa0[rg * 4 + 1] * inv);
    const unsigned u1 = pkbf(oa0[rg * 4 + 2] * inv, oa0[rg * 4 + 3] * inv);
    uint2 st = { u0, u1 };
    *(uint2*)(op + rg * 8) = st;
    const unsigned v0 = pkbf(oa1[rg * 4 + 0] * inv, oa1[rg * 4 + 1] * inv);
    const unsigned v1 = pkbf(oa1[rg * 4 + 2] * inv, oa1[rg * 4 + 3] * inv);
    uint2 st2 = { v0, v1 };
    *(uint2*)(op + 32 + rg * 8) = st2;
  }
}

// ---------------- LayerNorm: fp32 in -> fp32 + bf16 out ----------------
__global__ __launch_bounds__(256) void ln_kernel(
    const float* __restrict__ y, const float* __restrict__ g, const float* __restrict__ be,
    float* __restrict__ xf, unsigned short* __restrict__ xb) {
  const int row = blockIdx.x;
  const int t = threadIdx.x;
  const float4 v = ((const float4*)(y + (size_t)row * HDIM))[t];
  float s  = v.x + v.y + v.z + v.w;
  float ss = v.x*v.x + v.y*v.y + v.z*v.z + v.w*v.w;
#pragma unroll
  for (int m = 1; m < 64; m <<= 1) { s += __shfl_xor(s, m); ss += __shfl_xor(ss, m); }
  __shared__ float rs[4], rss[4];
  const int w = t >> 6, lane = t & 63;
  if (lane == 0) { rs[w] = s; rss[w] = ss; }
  __syncthreads();
  s  = rs[0] + rs[1] + rs[2] + rs[3];
  ss = rss[0] + rss[1] + rss[2] + rss[3];
  const float mean = s * (1.f / HDIM);
  const float inv = rsqrtf(ss * (1.f / HDIM) - mean * mean + 1e-5f);
  const int c = t * 4;
  const float4 gg = *(const float4*)(g + c);
  const float4 bb = *(const float4*)(be + c);
  float4 o;
  o.x = (v.x - mean) * inv * gg.x + bb.x;
  o.y = (v.y - mean) * inv * gg.y + bb.y;
  o.z = (v.z - mean) * inv * gg.z + bb.z;
  o.w = (v.w - mean) * inv * gg.w + bb.w;
  ((float4*)(xf + (size_t)row * HDIM))[t] = o;
  ushort4 ob = { f2b(o.x), f2b(o.y), f2b(o.z), f2b(o.w) };
  ((ushort4*)(xb + (size_t)row * HDIM))[t] = ob;
}

// ---------------- host ----------------
extern "C" void kernel_launch(void* const* d_in, const int* in_sizes, int n_in,
                              void* d_out, int out_size, void* d_ws, size_t ws_size,
                              hipStream_t stream) {
  const float* input_x = (const float*)d_in[0];
  const float* emb_W   = (const float*)d_in[1];
  const float* emb_b   = (const float*)d_in[2];
  const float* pos_tab = (const float*)d_in[3];
  const float* Wq  = (const float*)d_in[4];
  const float* bq  = (const float*)d_in[5];
  const float* Wk  = (const float*)d_in[6];
  const float* bk  = (const float*)d_in[7];
  const float* Wv  = (const float*)d_in[8];
  const float* bv  = (const float*)d_in[9];
  const float* Wo  = (const float*)d_in[10];
  const float* bo  = (const float*)d_in[11];
  const float* ln1g = (const float*)d_in[12];
  const float* ln1b = (const float*)d_in[13];
  const float* W1  = (const float*)d_in[14];
  const float* b1  = (const float*)d_in[15];
  const float* W2  = (const float*)d_in[16];
  const float* b2  = (const float*)d_in[17];
  const float* ln2g = (const float*)d_in[18];
  const float* ln2b = (const float*)d_in[19];
  float* out = (float*)d_out;

  char* ws = (char*)d_ws;
  size_t off = 0;
  auto alloc = [&](size_t bytes) {
    char* p = ws + off;
    off += (bytes + 255) & ~(size_t)255;
    return p;
  };
  unsigned short* wqkvT = (unsigned short*)alloc((size_t)3072 * HDIM * 2);
  unsigned short* woT   = (unsigned short*)alloc((size_t)HDIM * HDIM * 2);
  unsigned short* w1T   = (unsigned short*)alloc((size_t)PFF * HDIM * 2);   // [PF][H]
  unsigned short* w2T   = (unsigned short*)alloc((size_t)HDIM * PFF * 2);   // [H][PF]
  unsigned short* embWT = (unsigned short*)alloc((size_t)HDIM * 256 * 2);   // [H][IN]
  float*          bqkv  = (float*)alloc(3072 * 4);
  unsigned short* inb   = (unsigned short*)alloc((size_t)MM * 256 * 2);
  unsigned short* xb    = (unsigned short*)alloc((size_t)MM * HDIM * 2);
  unsigned short* qkvb  = (unsigned short*)alloc((size_t)MM * 3072 * 2);    // 48MB
  unsigned short* vtb   = (unsigned short*)alloc((size_t)MM * HDIM * 2);    // 16MB
  unsigned short* ab    = (unsigned short*)alloc((size_t)MM * HDIM * 2);
  float* y = (float*)alloc((size_t)MM * HDIM * 4);
  unsigned short* hb = qkvb;   // FFN hidden [M][4096] spans qkvb+vtb (dead by FFN1)

  const dim3 blk256(256);
  const dim3 blk512(512);
  const dim3 tblk(32, 8);

  // prep
  cvt_bf16<<<dim3(MM * 256 / 4 / 256), blk256, 0, stream>>>(input_x, inb, MM * 256 / 4);
  transpose_bf16<<<dim3(HDIM / 32, 256 / 32), tblk, 0, stream>>>(emb_W, embWT, 256, HDIM);

  // embedding: x = (input @ embW + b)*32 + pos   -> out(fp32) + xb(bf16)
  gemm2b<128, true, false, false, true, true, true><<<dim3(HDIM / 128, MM / 256), blk512, 0, stream>>>(
      inb, embWT, emb_b, nullptr, pos_tab, out, xb, MM, HDIM, 256);

  for (int l = 0; l < NLAYER; ++l) {
    const size_t wofs = (size_t)l * HDIM * HDIM;
    transpose_bf16<<<dim3(32, 32), tblk, 0, stream>>>(Wq + wofs, wqkvT,               HDIM, HDIM);
    transpose_bf16<<<dim3(32, 32), tblk, 0, stream>>>(Wk + wofs, wqkvT + 1024 * 1024, HDIM, HDIM);
    transpose_bf16<<<dim3(32, 32), tblk, 0, stream>>>(Wv + wofs, wqkvT + 2048 * 1024, HDIM, HDIM);
    transpose_bf16<<<dim3(32, 32), tblk, 0, stream>>>(Wo + wofs, woT, HDIM, HDIM);
    transpose_bf16<<<dim3(PFF / 32, HDIM / 32), tblk, 0, stream>>>(
        W1 + (size_t)l * HDIM * PFF, w1T, HDIM, PFF);
    transpose_bf16<<<dim3(HDIM / 32, PFF / 32), tblk, 0, stream>>>(
        W2 + (size_t)l * PFF * HDIM, w2T, PFF, HDIM);
    concat_bias<<<dim3(12), blk256, 0, stream>>>(bq + l * HDIM, bk + l * HDIM, bv + l * HDIM, bqkv);

    // fused QKV GEMM -> qkvb [M][3072]
    gemm2b<256, true, false, false, false, false, true><<<dim3(3072 / 256, MM / 256), blk512, 0, stream>>>(
        xb, wqkvT, bqkv, nullptr, nullptr, nullptr, qkvb, MM, 3072, HDIM);

    // V^T per head
    vtrans<<<dim3(32, 256), tblk, 0, stream>>>(qkvb, vtb);

    // attention
    attn2<<<dim3(SS / 128, BB * NHEAD), blk256, 0, stream>>>(qkvb, vtb, ab);

    // O-proj + residual (resid = fp32 x in `out`)
    gemm2b<128, true, false, true, false, true, false><<<dim3(HDIM / 128, MM / 256), blk512, 0, stream>>>(
        ab, woT, bo + l * HDIM, out, nullptr, y, nullptr, MM, HDIM, HDIM);
    ln_kernel<<<dim3(MM), blk256, 0, stream>>>(y, ln1g + l * HDIM, ln1b + l * HDIM, out, xb);

    // FFN
    gemm2b<256, true, true, false, false, false, true><<<dim3(PFF / 256, MM / 256), blk512, 0, stream>>>(
        xb, w1T, b1 + (size_t)l * PFF, nullptr, nullptr, nullptr, hb, MM, PFF, HDIM);
    gemm2b<128, true, false, true, false, true, false><<<dim3(HDIM / 128, MM / 256), blk512, 0, stream>>>(
        hb, w2T, b2 + l * HDIM, out, nullptr, y, nullptr, MM, HDIM, PFF);
    ln_kernel<<<dim3(MM), blk256, 0, stream>>>(y, ln2g + l * HDIM, ln2b + l * HDIM, out, xb);
  }
  (void)in_sizes; (void)n_in; (void)out_size; (void)ws_size;
}

// Round 8
// 2195.133 us; speedup vs baseline: 1.0453x; 1.0109x over previous
//
#include <hip/hip_runtime.h>

// ---------------- constants ----------------
#define HDIM 1024
#define BB 8
#define SS 1024
#define NHEAD 16
#define PFF 4096
#define NLAYER 6
#define MM (BB*SS)   // 8192 rows

typedef __attribute__((ext_vector_type(8))) short bf16x8_t;
typedef __attribute__((ext_vector_type(4))) float f32x4_t;
typedef __attribute__((ext_vector_type(16))) float f32x16_t;

static __device__ __forceinline__ unsigned short f2b(float f) {
  unsigned int u = __float_as_uint(f);
  u += 0x7fffu + ((u >> 16) & 1u);      // RNE
  return (unsigned short)(u >> 16);
}

static __device__ __forceinline__ unsigned pkbf(float lo, float hi) {
  unsigned r;
  asm("v_cvt_pk_bf16_f32 %0, %1, %2" : "=v"(r) : "v"(lo), "v"(hi));
  return r;
}

static __device__ __forceinline__ bf16x8_t mk8(unsigned a, unsigned b, unsigned c, unsigned d) {
  union { unsigned u[4]; bf16x8_t v; } x;
  x.u[0] = a; x.u[1] = b; x.u[2] = c; x.u[3] = d;
  return x.v;
}

static __device__ __forceinline__ void gload16(const void* g, void* l) {
  __builtin_amdgcn_global_load_lds((__attribute__((address_space(1))) void*)g,
                                   (__attribute__((address_space(3))) void*)l, 16, 0, 0);
}

template<int N>
static __device__ __forceinline__ void vwait() {
  asm volatile("s_waitcnt vmcnt(%0)" :: "n"(N) : "memory");
}

static __device__ __forceinline__ void bar() {
  asm volatile("" ::: "memory");
  __builtin_amdgcn_s_barrier();
  asm volatile("" ::: "memory");
}

// ---------------- fp32 -> bf16 convert ----------------
__global__ __launch_bounds__(256) void cvt_bf16(const float* __restrict__ in,
                                                unsigned short* __restrict__ o, int n4) {
  const int i = blockIdx.x * 256 + threadIdx.x;
  if (i < n4) {
    const float4 v = ((const float4*)in)[i];
    ushort4 ob = { f2b(v.x), f2b(v.y), f2b(v.z), f2b(v.w) };
    ((ushort4*)o)[i] = ob;
  }
}

// ---------------- transpose fp32 [R][C] -> bf16 [C][R] ----------------
__global__ __launch_bounds__(256) void transpose_bf16(const float* __restrict__ in,
                                                      unsigned short* __restrict__ outT,
                                                      int R, int C) {
  __shared__ float tile[32][33];
  const int c0 = blockIdx.x * 32, r0 = blockIdx.y * 32;
  const int tx = threadIdx.x, ty = threadIdx.y;   // (32,8)
#pragma unroll
  for (int i = 0; i < 4; ++i)
    tile[ty + 8*i][tx] = in[(size_t)(r0 + ty + 8*i) * C + c0 + tx];
  __syncthreads();
#pragma unroll
  for (int i = 0; i < 4; ++i)
    outT[(size_t)(c0 + ty + 8*i) * R + r0 + tx] = f2b(tile[tx][ty + 8*i]);
}

// ---------------- V^T extraction: qkv[M][3072] (V at col 2048+) -> vt[bh][64][1024] ----------------
__global__ __launch_bounds__(256) void vtrans(const unsigned short* __restrict__ qkv,
                                              unsigned short* __restrict__ vt) {
  __shared__ unsigned short tile[32][34];
  const int s0 = blockIdx.x * 32;
  const int by = blockIdx.y;           // bh*2 + dt
  const int bh = by >> 1, dt = by & 1;
  const int b = bh >> 4, h = bh & 15;
  const int tx = threadIdx.x, ty = threadIdx.y;  // (32,8)
  const unsigned short* src = qkv + ((size_t)(b * 1024 + s0)) * 3072 + 2048 + h * 64 + dt * 32;
#pragma unroll
  for (int i = 0; i < 4; ++i)
    tile[ty + 8*i][tx] = src[(size_t)(ty + 8*i) * 3072 + tx];
  __syncthreads();
  unsigned short* dst = vt + (size_t)(bh * 64 + dt * 32) * 1024 + s0;
#pragma unroll
  for (int i = 0; i < 4; ++i)
    dst[(size_t)(ty + 8*i) * 1024 + tx] = tile[tx][ty + 8*i];
}

// ---------------- bias concat for fused QKV ----------------
__global__ __launch_bounds__(256) void concat_bias(const float* __restrict__ bq,
                                                   const float* __restrict__ bk,
                                                   const float* __restrict__ bv,
                                                   float* __restrict__ o) {
  const int i = blockIdx.x * 256 + threadIdx.x;   // 0..3071
  o[i] = (i < 1024) ? bq[i] : ((i < 2048) ? bk[i - 1024] : bv[i - 2048]);
}

// ---------------- GEMM 256xBN, 8 waves (2x4), 16x16x32, pipelined 2-barrier K-tile ----------------
// R6-verified schedule (passed replay validation). BN in {128,192,256}.
// 4-phase (BN>=192): issue groups g0=[B0,B1] g1=[B2,(B3),A0] g2=[A2] g3=[A1,A3];
//   ph0 vwait(2) certifies {B*,A0,A2}; ph1 vwait(2) certifies {A1,A3}. Never drains mid-loop.
// 2-phase (BN=128): g0=[B0,B1,A0] g1=[A2,A1,A3]; vwait(2)/vwait(3).
template<int BN, bool BIAS, bool RELU, bool RESID, bool EMB, bool WF32, bool WBF16>
__global__ __launch_bounds__(512, 2) void gemm2c(
    const unsigned short* __restrict__ A,
    const unsigned short* __restrict__ Bt,
    const float* __restrict__ bias,
    const float* __restrict__ resid,
    const float* __restrict__ pos,
    float* __restrict__ outf,
    unsigned short* __restrict__ outb,
    int M, int N, int K) {
  constexpr int NJ = BN / 64;                    // B frags per wave (4, 3 or 2)
  constexpr int WCN = BN / 4;                    // per-wave col span
  constexpr int BUFSZ = 32768 + BN * 128;
  __shared__ __align__(1024) char smem[2 * BUFSZ];
  const int t = threadIdx.x, lane = t & 63, w = t >> 6;
  const int wr = w >> 2, wc = w & 3;             // 2x4 wave grid

  // bijective XCD swizzle (all grids divisible by 8)
  int flat = blockIdx.x + gridDim.x * blockIdx.y;
  const int cpx = (gridDim.x * gridDim.y) >> 3;
  flat = (flat & 7) * cpx + (flat >> 3);
  const int m0 = (flat / gridDim.x) * 256;
  const int n0 = (flat % gridDim.x) * BN;

  const f32x4_t z = {0.f, 0.f, 0.f, 0.f};
  f32x4_t acc[8][NJ];
#pragma unroll
  for (int i = 0; i < 8; ++i)
#pragma unroll
    for (int j = 0; j < NJ; ++j) acc[i][j] = z;

  auto stageA = [&](int i, int kt, int buf) {
    const int chunk = i * 8 + w;                 // band i = rows [64*i, +64)
    const int byteoff = chunk * 1024 + lane * 16;
    const int row = byteoff >> 7;
    const int scb = (byteoff & 127) ^ ((row & 7) << 4);
    gload16((const char*)A + ((size_t)(m0 + row) * K + (kt << 6)) * 2 + scb,
            smem + buf * BUFSZ + chunk * 1024);
  };
  auto stageB = [&](int i, int kt, int buf) {
    const int chunk = i * 8 + w;
    const int byteoff = chunk * 1024 + lane * 16;
    const int row = byteoff >> 7;
    const int scb = (byteoff & 127) ^ ((row & 7) << 4);
    gload16((const char*)Bt + ((size_t)(n0 + row) * K + (kt << 6)) * 2 + scb,
            smem + buf * BUFSZ + 32768 + chunk * 1024);
  };
  auto readA = [&](const char* ab, int fi, int ks) {
    const int row = wr * 128 + fi * 16 + (lane & 15);
    const int cb = ks * 64 + ((lane >> 4) << 4);
    return *(const bf16x8_t*)(ab + row * 128 + (cb ^ ((row & 7) << 4)));
  };
  auto readB = [&](const char* bb, int j, int ks) {
    const int row = wc * WCN + j * 16 + (lane & 15);
    const int cb = ks * 64 + ((lane >> 4) << 4);
    return *(const bf16x8_t*)(bb + row * 128 + (cb ^ ((row & 7) << 4)));
  };

  // prologue: tile 0 in need-order (B*, A0, A2, A1, A3)
  stageB(0, 0, 0); stageB(1, 0, 0);
  if constexpr (NJ >= 3) stageB(2, 0, 0);
  if constexpr (NJ >= 4) stageB(3, 0, 0);
  stageA(0, 0, 0); stageA(2, 0, 0); stageA(1, 0, 0); stageA(3, 0, 0);

  const int nkt = K >> 6;
  for (int kt = 0; kt < nkt; ++kt) {
    const char* ab = smem + (kt & 1) * BUFSZ;
    const char* bb = ab + 32768;
    const int nb = (kt & 1) ^ 1;
    const bool pf = (kt + 1 < nkt);
    bf16x8_t bfr[NJ][2], af[8][2];

    if constexpr (BN >= 192) {
      // ---- ph0: certify {B*,A0,A2}; read B + frags0-3; MFMA 0-1 ----
      vwait<2>(); bar();
      if (pf) { stageB(0, kt + 1, nb); stageB(1, kt + 1, nb); }
#pragma unroll
      for (int j = 0; j < NJ; ++j)
#pragma unroll
        for (int ks = 0; ks < 2; ++ks) bfr[j][ks] = readB(bb, j, ks);
#pragma unroll
      for (int d = 0; d < 4; ++d)
#pragma unroll
        for (int ks = 0; ks < 2; ++ks) af[d][ks] = readA(ab, d, ks);
      __builtin_amdgcn_s_setprio(1);
#pragma unroll
      for (int ks = 0; ks < 2; ++ks)
#pragma unroll
        for (int d = 0; d < 2; ++d)
#pragma unroll
          for (int j = 0; j < NJ; ++j)
            acc[d][j] = __builtin_amdgcn_mfma_f32_16x16x32_bf16(af[d][ks], bfr[j][ks], acc[d][j], 0, 0, 0);
      __builtin_amdgcn_s_setprio(0);
      // ---- ph1: certify {A1,A3}; read frags4-5; MFMA 2-3 ----
      if (pf) vwait<2>(); else vwait<0>();
      bar();
      if (pf) {
        stageB(2, kt + 1, nb);
        if constexpr (NJ >= 4) stageB(3, kt + 1, nb);
        stageA(0, kt + 1, nb);
      }
#pragma unroll
      for (int d = 4; d < 6; ++d)
#pragma unroll
        for (int ks = 0; ks < 2; ++ks) af[d][ks] = readA(ab, d, ks);
      __builtin_amdgcn_s_setprio(1);
#pragma unroll
      for (int ks = 0; ks < 2; ++ks)
#pragma unroll
        for (int d = 2; d < 4; ++d)
#pragma unroll
          for (int j = 0; j < NJ; ++j)
            acc[d][j] = __builtin_amdgcn_mfma_f32_16x16x32_bf16(af[d][ks], bfr[j][ks], acc[d][j], 0, 0, 0);
      __builtin_amdgcn_s_setprio(0);
      // ---- ph2: read frags6-7; MFMA 4-5 ----
      if (pf) stageA(2, kt + 1, nb);
#pragma unroll
      for (int d = 6; d < 8; ++d)
#pragma unroll
        for (int ks = 0; ks < 2; ++ks) af[d][ks] = readA(ab, d, ks);
      __builtin_amdgcn_s_setprio(1);
#pragma unroll
      for (int ks = 0; ks < 2; ++ks)
#pragma unroll
        for (int d = 4; d < 6; ++d)
#pragma unroll
          for (int j = 0; j < NJ; ++j)
            acc[d][j] = __builtin_amdgcn_mfma_f32_16x16x32_bf16(af[d][ks], bfr[j][ks], acc[d][j], 0, 0, 0);
      __builtin_amdgcn_s_setprio(0);
      // ---- ph3: MFMA 6-7 (frags resident) ----
      if (pf) { stageA(1, kt + 1, nb); stageA(3, kt + 1, nb); }
      __builtin_amdgcn_s_setprio(1);
#pragma unroll
      for (int ks = 0; ks < 2; ++ks)
#pragma unroll
        for (int d = 6; d < 8; ++d)
#pragma unroll
          for (int j = 0; j < NJ; ++j)
            acc[d][j] = __builtin_amdgcn_mfma_f32_16x16x32_bf16(af[d][ks], bfr[j][ks], acc[d][j], 0, 0, 0);
      __builtin_amdgcn_s_setprio(0);
    } else {
      // ---- BN=128, ph0: certify {B*,A0,A2}; read B + frags0-3; MFMA 0-3 ----
      vwait<2>(); bar();
      if (pf) { stageB(0, kt + 1, nb); stageB(1, kt + 1, nb); stageA(0, kt + 1, nb); }
#pragma unroll
      for (int j = 0; j < NJ; ++j)
#pragma unroll
        for (int ks = 0; ks < 2; ++ks) bfr[j][ks] = readB(bb, j, ks);
#pragma unroll
      for (int d = 0; d < 4; ++d)
#pragma unroll
        for (int ks = 0; ks < 2; ++ks) af[d][ks] = readA(ab, d, ks);
      __builtin_amdgcn_s_setprio(1);
#pragma unroll
      for (int ks = 0; ks < 2; ++ks)
#pragma unroll
        for (int d = 0; d < 4; ++d)
#pragma unroll
          for (int j = 0; j < NJ; ++j)
            acc[d][j] = __builtin_amdgcn_mfma_f32_16x16x32_bf16(af[d][ks], bfr[j][ks], acc[d][j], 0, 0, 0);
      __builtin_amdgcn_s_setprio(0);
      // ---- ph1: certify {A1,A3}; read frags4-7; MFMA 4-7 ----
      if (pf) vwait<3>(); else vwait<0>();
      bar();
      if (pf) { stageA(2, kt + 1, nb); stageA(1, kt + 1, nb); stageA(3, kt + 1, nb); }
#pragma unroll
      for (int d = 4; d < 8; ++d)
#pragma unroll
        for (int ks = 0; ks < 2; ++ks) af[d][ks] = readA(ab, d, ks);
      __builtin_amdgcn_s_setprio(1);
#pragma unroll
      for (int ks = 0; ks < 2; ++ks)
#pragma unroll
        for (int d = 4; d < 8; ++d)
#pragma unroll
          for (int j = 0; j < NJ; ++j)
            acc[4 > d ? 0 : d][j] = __builtin_amdgcn_mfma_f32_16x16x32_bf16(af[d][ks], bfr[j][ks], acc[d][j], 0, 0, 0);
      __builtin_amdgcn_s_setprio(0);
    }
  }

  // epilogue: C/D layout col=lane&15, row=(lane>>4)*4+r
#pragma unroll
  for (int i = 0; i < 8; ++i) {
    const int rbase = m0 + wr * 128 + i * 16 + ((lane >> 4) << 2);
#pragma unroll
    for (int j = 0; j < NJ; ++j) {
      const int cc = n0 + wc * WCN + j * 16 + (lane & 15);
      float bv = 0.f;
      if (BIAS) bv = bias[cc];
#pragma unroll
      for (int r = 0; r < 4; ++r) {
        const int row = rbase + r;
        float v = acc[i][j][r] + bv;
        if (EMB)  v = v * 32.f + pos[(size_t)(row & (SS - 1)) * N + cc];
        if (RELU) v = fmaxf(v, 0.f);
        if (RESID) v += resid[(size_t)row * N + cc];
        if (WF32)  outf[(size_t)row * N + cc] = v;
        if (WBF16) outb[(size_t)row * N + cc] = f2b(v);
      }
    }
  }
}

// ---------------- flash attention, swapped-QK^T in-register softmax ----------------
__global__ __launch_bounds__(256) void attn2(
    const unsigned short* __restrict__ qkv,   // [M][3072]: Q|K|V
    const unsigned short* __restrict__ vt,    // [bh][64][1024] = V^T per head
    unsigned short* __restrict__ O) {         // [M][1024]
  __shared__ __align__(1024) char smem[2 * 16384];   // dbuf x (K 8KB | VT 8KB)
  const int t = threadIdx.x, lane = t & 63, w = t >> 6;
  const int l31 = lane & 31, lg = lane >> 5;   // lane group (0/1)
  const int bh = blockIdx.y;
  const int b = bh >> 4, h = bh & 15;
  const size_t rowb = (size_t)b << 10;
  const int q0 = blockIdx.x * 128 + w * 32;

  bf16x8_t qf[4];
  {
    const unsigned short* Qp = qkv + (rowb + q0 + l31) * 3072 + h * 64 + lg * 8;
#pragma unroll
    for (int dd = 0; dd < 4; ++dd) qf[dd] = *(const bf16x8_t*)(Qp + dd * 16);
  }

  f32x16_t oa0, oa1;
#pragma unroll
  for (int r = 0; r < 16; ++r) { oa0[r] = 0.f; oa1[r] = 0.f; }
  float m_run = -1e30f, l_run = 0.f;
  const float inv32 = 1.f / 32.f;

  const char* kglob = (const char*)qkv + ((size_t)1024 + h * 64) * 2;
  const char* vglob = (const char*)vt + (size_t)bh * 64 * 1024 * 2;

  auto stage = [&](int kt, int buf) {
    char* kbuf = smem + buf * 16384;
    char* vbuf = kbuf + 8192;
#pragma unroll
    for (int i = 0; i < 2; ++i) {
      const int chunk = w * 2 + i;                 // 0..7
      const int byteoff = chunk * 1024 + lane * 16;
      const int row = byteoff >> 7;                // 0..63
      const int scb = (byteoff & 127) ^ ((row & 7) << 4);
      gload16(kglob + (size_t)(rowb + kt * 64 + row) * 6144 + scb, kbuf + chunk * 1024);
      gload16(vglob + ((size_t)row * 1024 + kt * 64) * 2 + scb,    vbuf + chunk * 1024);
    }
  };

  stage(0, 0);
  for (int kt = 0; kt < 16; ++kt) {
    const int cb = kt & 1;
    __syncthreads();
    if (kt < 15) stage(kt + 1, cb ^ 1);
    const char* kbuf = smem + cb * 16384;
    const char* vbuf = kbuf + 8192;

    f32x16_t p0, p1;
#pragma unroll
    for (int r = 0; r < 16; ++r) { p0[r] = 0.f; p1[r] = 0.f; }
    __builtin_amdgcn_s_setprio(1);
#pragma unroll
    for (int dd = 0; dd < 4; ++dd) {
      {
        const int row = l31;
        const int col = (dd * 32 + (lg << 4)) ^ ((row & 7) << 4);
        bf16x8_t kf = *(const bf16x8_t*)(kbuf + row * 128 + col);
        p0 = __builtin_amdgcn_mfma_f32_32x32x16_bf16(kf, qf[dd], p0, 0, 0, 0);
      }
      {
        const int row = 32 + l31;
        const int col = (dd * 32 + (lg << 4)) ^ ((row & 7) << 4);
        bf16x8_t kf = *(const bf16x8_t*)(kbuf + row * 128 + col);
        p1 = __builtin_amdgcn_mfma_f32_32x32x16_bf16(kf, qf[dd], p1, 0, 0, 0);
      }
    }
    __builtin_amdgcn_s_setprio(0);

    float mx = p0[0];
#pragma unroll
    for (int r = 1; r < 16; ++r) mx = fmaxf(mx, p0[r]);
#pragma unroll
    for (int r = 0; r < 16; ++r) mx = fmaxf(mx, p1[r]);
    mx = fmaxf(mx, __shfl_xor(mx, 32));
    const float mn = fmaxf(m_run, mx * inv32);
    const float fr = __expf(m_run - mn);
    m_run = mn;
    float sum = 0.f;
#pragma unroll
    for (int r = 0; r < 16; ++r) { const float e = __expf(p0[r] * inv32 - mn); p0[r] = e; sum += e; }
#pragma unroll
    for (int r = 0; r < 16; ++r) { const float e = __expf(p1[r] * inv32 - mn); p1[r] = e; sum += e; }
    sum += __shfl_xor(sum, 32);
    l_run = l_run * fr + sum;
#pragma unroll
    for (int r = 0; r < 16; ++r) { oa0[r] *= fr; oa1[r] *= fr; }

    const unsigned A0 = pkbf(p0[0], p0[1]),  B0 = pkbf(p0[2], p0[3]);
    const unsigned C0 = pkbf(p0[4], p0[5]),  D0 = pkbf(p0[6], p0[7]);
    const unsigned E0 = pkbf(p0[8], p0[9]),  F0 = pkbf(p0[10], p0[11]);
    const unsigned G0 = pkbf(p0[12], p0[13]), H0 = pkbf(p0[14], p0[15]);
    const unsigned A1 = pkbf(p1[0], p1[1]),  B1 = pkbf(p1[2], p1[3]);
    const unsigned C1 = pkbf(p1[4], p1[5]),  D1 = pkbf(p1[6], p1[7]);
    const unsigned E1 = pkbf(p1[8], p1[9]),  F1 = pkbf(p1[10], p1[11]);
    const unsigned G1 = pkbf(p1[12], p1[13]), H1 = pkbf(p1[14], p1[15]);
    const unsigned sA0 = __shfl_xor((int)A0, 32), sB0 = __shfl_xor((int)B0, 32);
    const unsigned sC0 = __shfl_xor((int)C0, 32), sD0 = __shfl_xor((int)D0, 32);
    const unsigned sE0 = __shfl_xor((int)E0, 32), sF0 = __shfl_xor((int)F0, 32);
    const unsigned sG0 = __shfl_xor((int)G0, 32), sH0 = __shfl_xor((int)H0, 32);
    const unsigned sA1 = __shfl_xor((int)A1, 32), sB1 = __shfl_xor((int)B1, 32);
    const unsigned sC1 = __shfl_xor((int)C1, 32), sD1 = __shfl_xor((int)D1, 32);
    const unsigned sE1 = __shfl_xor((int)E1, 32), sF1 = __shfl_xor((int)F1, 32);
    const unsigned sG1 = __shfl_xor((int)G1, 32), sH1 = __shfl_xor((int)H1, 32);
    const bool hi = (lg != 0);
    bf16x8_t pf[4];
    pf[0] = hi ? mk8(sC0, sD0, C0, D0) : mk8(A0, B0, sA0, sB0);
    pf[1] = hi ? mk8(sG0, sH0, G0, H0) : mk8(E0, F0, sE0, sF0);
    pf[2] = hi ? mk8(sC1, sD1, C1, D1) : mk8(A1, B1, sA1, sB1);
    pf[3] = hi ? mk8(sG1, sH1, G1, H1) : mk8(E1, F1, sE1, sF1);

    __builtin_amdgcn_s_setprio(1);
#pragma unroll
    for (int c = 0; c < 4; ++c) {
      {
        const int row = l31;
        const int col = (c * 32 + (lg << 4)) ^ ((row & 7) << 4);
        bf16x8_t vf = *(const bf16x8_t*)(vbuf + row * 128 + col);
        oa0 = __builtin_amdgcn_mfma_f32_32x32x16_bf16(vf, pf[c], oa0, 0, 0, 0);
      }
      {
        const int row = 32 + l31;
        const int col = (c * 32 + (lg << 4)) ^ ((row & 7) << 4);
        bf16x8_t vf = *(const bf16x8_t*)(vbuf + row * 128 + col);
        oa1 = __builtin_amdgcn_mfma_f32_32x32x16_bf16(vf, pf[c], oa1, 0, 0, 0);
      }
    }
    __builtin_amdgcn_s_setprio(0);
  }

  const float inv = 1.f / l_run;
  unsigned short* op = O + (rowb + q0 + l31) * 1024 + h * 64 + (lg << 2);
#pragma unroll
  for (int rg = 0; rg < 4; ++rg) {
    const unsigned u0 = pkbf(oa0[rg * 4 + 0] * inv, oa0[rg * 4 + 1] * inv);
    const unsigned u1 = pkbf(oa0[rg * 4 + 2] * inv, oa0[rg * 4 + 3] * inv);
    uint2 st = { u0, u1 };
    *(uint2*)(op + rg * 8) = st;
    const unsigned v0 = pkbf(oa1[rg * 4 + 0] * inv, oa1[rg * 4 + 1] * inv);
    const unsigned v1 = pkbf(oa1[rg * 4 + 2] * inv, oa1[rg * 4 + 3] * inv);
    uint2 st2 = { v0, v1 };
    *(uint2*)(op + 32 + rg * 8) = st2;
  }
}

// ---------------- LayerNorm: fp32 in -> fp32 + bf16 out ----------------
__global__ __launch_bounds__(256) void ln_kernel(
    const float* __restrict__ y, const float* __restrict__ g, const float* __restrict__ be,
    float* __restrict__ xf, unsigned short* __restrict__ xb) {
  const int row = blockIdx.x;
  const int t = threadIdx.x;
  const float4 v = ((const float4*)(y + (size_t)row * HDIM))[t];
  float s  = v.x + v.y + v.z + v.w;
  float ss = v.x*v.x + v.y*v.y + v.z*v.z + v.w*v.w;
#pragma unroll
  for (int m = 1; m < 64; m <<= 1) { s += __shfl_xor(s, m); ss += __shfl_xor(ss, m); }
  __shared__ float rs[4], rss[4];
  const int w = t >> 6, lane = t & 63;
  if (lane == 0) { rs[w] = s; rss[w] = ss; }
  __syncthreads();
  s  = rs[0] + rs[1] + rs[2] + rs[3];
  ss = rss[0] + rss[1] + rss[2] + rss[3];
  const float mean = s * (1.f / HDIM);
  const float inv = rsqrtf(ss * (1.f / HDIM) - mean * mean + 1e-5f);
  const int c = t * 4;
  const float4 gg = *(const float4*)(g + c);
  const float4 bb = *(const float4*)(be + c);
  float4 o;
  o.x = (v.x - mean) * inv * gg.x + bb.x;
  o.y = (v.y - mean) * inv * gg.y + bb.y;
  o.z = (v.z - mean) * inv * gg.z + bb.z;
  o.w = (v.w - mean) * inv * gg.w + bb.w;
  ((float4*)(xf + (size_t)row * HDIM))[t] = o;
  ushort4 ob = { f2b(o.x), f2b(o.y), f2b(o.z), f2b(o.w) };
  ((ushort4*)(xb + (size_t)row * HDIM))[t] = ob;
}

// ---------------- host ----------------
extern "C" void kernel_launch(void* const* d_in, const int* in_sizes, int n_in,
                              void* d_out, int out_size, void* d_ws, size_t ws_size,
                              hipStream_t stream) {
  const float* input_x = (const float*)d_in[0];
  const float* emb_W   = (const float*)d_in[1];
  const float* emb_b   = (const float*)d_in[2];
  const float* pos_tab = (const float*)d_in[3];
  const float* Wq  = (const float*)d_in[4];
  const float* bq  = (const float*)d_in[5];
  const float* Wk  = (const float*)d_in[6];
  const float* bk  = (const float*)d_in[7];
  const float* Wv  = (const float*)d_in[8];
  const float* bv  = (const float*)d_in[9];
  const float* Wo  = (const float*)d_in[10];
  const float* bo  = (const float*)d_in[11];
  const float* ln1g = (const float*)d_in[12];
  const float* ln1b = (const float*)d_in[13];
  const float* W1  = (const float*)d_in[14];
  const float* b1  = (const float*)d_in[15];
  const float* W2  = (const float*)d_in[16];
  const float* b2  = (const float*)d_in[17];
  const float* ln2g = (const float*)d_in[18];
  const float* ln2b = (const float*)d_in[19];
  float* out = (float*)d_out;

  char* ws = (char*)d_ws;
  size_t off = 0;
  auto alloc = [&](size_t bytes) {
    char* p = ws + off;
    off += (bytes + 255) & ~(size_t)255;
    return p;
  };
  unsigned short* wqkvT = (unsigned short*)alloc((size_t)3072 * HDIM * 2);
  unsigned short* woT   = (unsigned short*)alloc((size_t)HDIM * HDIM * 2);
  unsigned short* w1T   = (unsigned short*)alloc((size_t)PFF * HDIM * 2);   // [PF][H]
  unsigned short* w2T   = (unsigned short*)alloc((size_t)HDIM * PFF * 2);   // [H][PF]
  unsigned short* embWT = (unsigned short*)alloc((size_t)HDIM * 256 * 2);   // [H][IN]
  float*          bqkv  = (float*)alloc(3072 * 4);
  unsigned short* inb   = (unsigned short*)alloc((size_t)MM * 256 * 2);
  unsigned short* xb    = (unsigned short*)alloc((size_t)MM * HDIM * 2);
  unsigned short* qkvb  = (unsigned short*)alloc((size_t)MM * 3072 * 2);    // 48MB
  unsigned short* vtb   = (unsigned short*)alloc((size_t)MM * HDIM * 2);    // 16MB
  unsigned short* ab    = (unsigned short*)alloc((size_t)MM * HDIM * 2);
  float* y = (float*)alloc((size_t)MM * HDIM * 4);
  unsigned short* hb = qkvb;   // FFN hidden [M][4096] spans qkvb+vtb (dead by FFN1)

  const dim3 blk256(256);
  const dim3 blk512(512);
  const dim3 tblk(32, 8);

  // prep
  cvt_bf16<<<dim3(MM * 256 / 4 / 256), blk256, 0, stream>>>(input_x, inb, MM * 256 / 4);
  transpose_bf16<<<dim3(HDIM / 32, 256 / 32), tblk, 0, stream>>>(emb_W, embWT, 256, HDIM);

  // embedding: x = (input @ embW + b)*32 + pos   -> out(fp32) + xb(bf16)
  gemm2c<128, true, false, false, true, true, true><<<dim3(HDIM / 128, MM / 256), blk512, 0, stream>>>(
      inb, embWT, emb_b, nullptr, pos_tab, out, xb, MM, HDIM, 256);

  for (int l = 0; l < NLAYER; ++l) {
    const size_t wofs = (size_t)l * HDIM * HDIM;
    transpose_bf16<<<dim3(32, 32), tblk, 0, stream>>>(Wq + wofs, wqkvT,               HDIM, HDIM);
    transpose_bf16<<<dim3(32, 32), tblk, 0, stream>>>(Wk + wofs, wqkvT + 1024 * 1024, HDIM, HDIM);
    transpose_bf16<<<dim3(32, 32), tblk, 0, stream>>>(Wv + wofs, wqkvT + 2048 * 1024, HDIM, HDIM);
    transpose_bf16<<<dim3(32, 32), tblk, 0, stream>>>(Wo + wofs, woT, HDIM, HDIM);
    transpose_bf16<<<dim3(PFF / 32, HDIM / 32), tblk, 0, stream>>>(
        W1 + (size_t)l * HDIM * PFF, w1T, HDIM, PFF);
    transpose_bf16<<<dim3(HDIM / 32, PFF / 32), tblk, 0, stream>>>(
        W2 + (size_t)l * PFF * HDIM, w2T, PFF, HDIM);
    concat_bias<<<dim3(12), blk256, 0, stream>>>(bq + l * HDIM, bk + l * HDIM, bv + l * HDIM, bqkv);

    // fused QKV GEMM -> qkvb [M][3072]  (BN=192 -> grid 512 = exactly 2 CU-rounds)
    gemm2c<192, true, false, false, false, false, true><<<dim3(3072 / 192, MM / 256), blk512, 0, stream>>>(
        xb, wqkvT, bqkv, nullptr, nullptr, nullptr, qkvb, MM, 3072, HDIM);

    // V^T per head
    vtrans<<<dim3(32, 256), tblk, 0, stream>>>(qkvb, vtb);

    // attention
    attn2<<<dim3(SS / 128, BB * NHEAD), blk256, 0, stream>>>(qkvb, vtb, ab);

    // O-proj + residual (resid = fp32 x in `out`)
    gemm2c<128, true, false, true, false, true, false><<<dim3(HDIM / 128, MM / 256), blk512, 0, stream>>>(
        ab, woT, bo + l * HDIM, out, nullptr, y, nullptr, MM, HDIM, HDIM);
    ln_kernel<<<dim3(MM), blk256, 0, stream>>>(y, ln1g + l * HDIM, ln1b + l * HDIM, out, xb);

    // FFN
    gemm2c<256, true, true, false, false, false, true><<<dim3(PFF / 256, MM / 256), blk512, 0, stream>>>(
        xb, w1T, b1 + (size_t)l * PFF, nullptr, nullptr, nullptr, hb, MM, PFF, HDIM);
    gemm2c<128, true, false, true, false, true, false><<<dim3(HDIM / 128, MM / 256), blk512, 0, stream>>>(
        hb, w2T, b2 + l * HDIM, out, nullptr, y, nullptr, MM, HDIM, PFF);
    ln_kernel<<<dim3(MM), blk256, 0, stream>>>(y, ln2g + l * HDIM, ln2b + l * HDIM, out, xb);
  }
  (void)in_sizes; (void)n_in; (void)out_size; (void)ws_size;
}